// Round 7
// baseline (218.775 us; speedup 1.0000x reference)
//
#include <hip/hip_runtime.h>
#include <stdint.h>

// ---------------- problem constants ----------------
#define BHN 16          // b*h flat batch
#define TLEN 4096
#define EDIM 64
#define NHASH 8
#define NBUCK 64
#define GBUCK 512
#define NCHUNK 512
#define NITEMS 32768

// ---------------- workspace layout (bytes) ----------------
#define WS_BUCKETS 0u                 // 16*8*4096 u8          = 524288
#define WS_STARTS  524288u            // 16*512 int            = 32768
#define WS_SORTED  557056u            // 16*32768 int          = 2097152
#define WS_LSE     2654208u           // 16*8*4096 f32         = 2097152
#define WS_O       4751360u           // 16*8*4096*64 fp16     = 67108864
#define WS_QK16    71860224u          // 16*4096*64 fp16       = 8388608
#define WS_V16     80248832u          // 16*4096*64 fp16       = 8388608
#define WS_NQ      88637440u          // 16*4096 f32           = 262144
// end ~88.9 MB

typedef __attribute__((ext_vector_type(4))) float f32x4;
typedef __attribute__((ext_vector_type(8))) _Float16 f16x8;     // MFMA A/B frag
typedef __attribute__((ext_vector_type(4))) _Float16 f16x4;
typedef __attribute__((ext_vector_type(4))) unsigned u32x4;

#define LOG2E 1.44269504088896f
#define LN2   0.69314718055995f

// ============================================================
// K0: prep — normalize qk rows to fp16, |q|*log2e, v to fp16.
// ============================================================
__global__ __launch_bounds__(128) void k_prep(const float* __restrict__ qk,
                                              const float* __restrict__ vin,
                                              _Float16* __restrict__ qk16n,
                                              _Float16* __restrict__ v16,
                                              float* __restrict__ nq) {
  int blk = blockIdx.x;             // 8192 = b*4096 + t
  int b = blk >> 12, t = blk & 4095;
  int tid = threadIdx.x;
  int h = tid >> 4, e4 = tid & 15;

  size_t in_base = ((size_t)((b * 4096 + t) * 8 + h)) * 64 + e4 * 4;
  float4 qv = *(const float4*)(qk + in_base);
  float ss = qv.x * qv.x + qv.y * qv.y + qv.z * qv.z + qv.w * qv.w;
  ss += __shfl_xor(ss, 1);
  ss += __shfl_xor(ss, 2);
  ss += __shfl_xor(ss, 4);
  ss += __shfl_xor(ss, 8);
  float nrm = fmaxf(sqrtf(ss), 1e-12f);
  float inv = 1.f / nrm;

  size_t out_base = ((size_t)((b * 8 + h) * 4096 + t)) * 64 + e4 * 4;
  f16x4 qh;
  qh[0] = (_Float16)(qv.x * inv); qh[1] = (_Float16)(qv.y * inv);
  qh[2] = (_Float16)(qv.z * inv); qh[3] = (_Float16)(qv.w * inv);
  *(f16x4*)(qk16n + out_base) = qh;
  if (e4 == 0) nq[(size_t)(b * 8 + h) * 4096 + t] = nrm * LOG2E;

  float4 vv = *(const float4*)(vin + in_base);
  f16x4 vh;
  vh[0] = (_Float16)vv.x; vh[1] = (_Float16)vv.y;
  vh[2] = (_Float16)vv.z; vh[3] = (_Float16)vv.w;
  *(f16x4*)(v16 + out_base) = vh;
}

// ============================================================
// K1: LSH hash — zero-LDS, fp32, 2 TOKENS PER THREAD.
// Per s_load'ed rot row (32 SGPR floats) we now issue 128
// FMA-cycles (2 tokens x 32 i) instead of 64, hiding the
// scalar-load latency that capped round 6 at VALUBusy 41%.
// Per-token fmaf order (f ascending) and argmax scan identical
// to all passing rounds -> bit-identical buckets.
// Full unroll everywhere: q0/q1/acc must stay compile-time
// indexed or they demote to scratch (rule #20, round-5 lesson).
// ============================================================
__global__ __launch_bounds__(256) void k_hash(const float* __restrict__ qk,
                                              const float* __restrict__ rot,
                                              uint8_t* __restrict__ buckets,
                                              int* __restrict__ counts) {
  int tid = threadIdx.x;
  int blk = blockIdx.x;                 // 512 blocks
  int bh   = blk >> 5;                  // 16
  int hp   = (blk >> 3) & 3;            // 4 hash pairs
  int tblk = blk & 7;                   // 8 token tiles
  int t0 = tblk * 512 + tid;
  int t1 = t0 + 256;
  int b = bh >> 3, head = bh & 7;

  const float4* r40 = (const float4*)(qk + ((size_t)((b * 4096 + t0) * 8 + head)) * 64);
  const float4* r41 = (const float4*)(qk + ((size_t)((b * 4096 + t1) * 8 + head)) * 64);
  float q0[64], q1[64];
#pragma unroll
  for (int f4 = 0; f4 < 16; ++f4) {
    float4 va = r40[f4];
    q0[4 * f4 + 0] = va.x; q0[4 * f4 + 1] = va.y;
    q0[4 * f4 + 2] = va.z; q0[4 * f4 + 3] = va.w;
    float4 vb = r41[f4];
    q1[4 * f4 + 0] = vb.x; q1[4 * f4 + 1] = vb.y;
    q1[4 * f4 + 2] = vb.z; q1[4 * f4 + 3] = vb.w;
  }

  for (int hh = 0; hh < 2; ++hh) {
    int h = hp * 2 + hh;
    const float* rbase = rot + h * 32;
    float a0[32], a1[32];
#pragma unroll
    for (int i = 0; i < 32; ++i) { a0[i] = 0.f; a1[i] = 0.f; }

#pragma unroll
    for (int f = 0; f < 64; ++f) {
      float qa = q0[f], qb = q1[f];
      const float* rp = rbase + f * 256;   // wave-uniform -> s_load
#pragma unroll
      for (int i = 0; i < 32; ++i) {
        float rv = rp[i];
        a0[i] = fmaf(qa, rv, a0[i]);
        a1[i] = fmaf(qb, rv, a1[i]);
      }
    }

    // argmax over concat([rot, -rot]), first-max semantics, per token
    {
      float bv = a0[0]; int bi = 0;
#pragma unroll
      for (int i = 1; i < 32; ++i) { if (a0[i] > bv) { bv = a0[i]; bi = i; } }
#pragma unroll
      for (int i = 0; i < 32; ++i) { float nv = -a0[i]; if (nv > bv) { bv = nv; bi = i + 32; } }
      buckets[(bh * 8 + h) * 4096 + t0] = (uint8_t)bi;
      atomicAdd(&counts[bh * 512 + h * 64 + bi], 1);
    }
    {
      float bv = a1[0]; int bi = 0;
#pragma unroll
      for (int i = 1; i < 32; ++i) { if (a1[i] > bv) { bv = a1[i]; bi = i; } }
#pragma unroll
      for (int i = 0; i < 32; ++i) { float nv = -a1[i]; if (nv > bv) { bv = nv; bi = i + 32; } }
      buckets[(bh * 8 + h) * 4096 + t1] = (uint8_t)bi;
      atomicAdd(&counts[bh * 512 + h * 64 + bi], 1);
    }
  }
}

// ============================================================
// K2a: exclusive scan (unchanged)
// ============================================================
__global__ __launch_bounds__(512) void k_scan(int* __restrict__ counts) {
  __shared__ int s[512];
  int tid = threadIdx.x;
  int bh = blockIdx.x;
  s[tid] = counts[bh * 512 + tid];
  __syncthreads();
#pragma unroll
  for (int off = 1; off < 512; off <<= 1) {
    int v = (tid >= off) ? s[tid - off] : 0;
    __syncthreads();
    s[tid] += v;
    __syncthreads();
  }
  counts[bh * 512 + tid] = (tid == 0) ? 0 : s[tid - 1];
}

// ============================================================
// K2b: stable rank + scatter (unchanged)
// ============================================================
__global__ __launch_bounds__(64) void k_rank(const uint8_t* __restrict__ buckets,
                                             const int* __restrict__ starts,
                                             int* __restrict__ sorted) {
  __shared__ uint8_t bkt[4096];
  __shared__ uint8_t lrk[4096];
  __shared__ int hist[64 * 65];
  __shared__ int sbase[64];
  int tid = threadIdx.x;
  int bh = blockIdx.x >> 3, h = blockIdx.x & 7;

  const int* src = (const int*)(buckets + (size_t)(bh * 8 + h) * 4096);
  for (int k = tid; k < 1024; k += 64) ((int*)bkt)[k] = src[k];
  sbase[tid] = starts[bh * 512 + h * 64 + tid];
  for (int k = tid; k < 64 * 65; k += 64) hist[k] = 0;
  __syncthreads();

  {
    int c = tid;
    for (int k = 0; k < 64; ++k) {
      int t = c * 64 + k;
      int bin = bkt[t];
      int r = hist[c * 65 + bin];
      hist[c * 65 + bin] = r + 1;
      lrk[t] = (uint8_t)r;
    }
  }
  __syncthreads();
  {
    int bb = tid; int run = 0;
    for (int c2 = 0; c2 < 64; ++c2) {
      int val = hist[c2 * 65 + bb];
      hist[c2 * 65 + bb] = run;
      run += val;
    }
  }
  __syncthreads();
  {
    int c = tid;
    int* dst = sorted + (size_t)bh * 32768;
    for (int k = 0; k < 64; ++k) {
      int t = c * 64 + k;
      int bin = bkt[t];
      int pos = sbase[bin] + hist[c * 65 + bin] + (int)lrk[t];
      dst[pos] = h * 4096 + t;
    }
  }
}

// ============================================================
// K3: chunked attention, fp16 MFMA (unchanged from round 5)
// ============================================================
__global__ __launch_bounds__(256, 4) void k_attn(const _Float16* __restrict__ qk16n,
                                                 const _Float16* __restrict__ v16,
                                                 const float* __restrict__ nq,
                                                 const int* __restrict__ sorted,
                                                 _Float16* __restrict__ o_buf,
                                                 float* __restrict__ lse_buf) {
  __shared__ __attribute__((aligned(16))) _Float16 kf[128 * 64];
  __shared__ __attribute__((aligned(16))) _Float16 vt[64 * 128];
  __shared__ __attribute__((aligned(16))) float pinv_s[64];
  __shared__ __attribute__((aligned(16))) int tv[128];
  __shared__ __attribute__((aligned(16))) int items[64];

  int tid = threadIdx.x;
  int bh = blockIdx.x >> 9;
  int c  = blockIdx.x & 511;

  // ---- step 1: item ids for 64 current + 64 look-back rows ----
  if (tid < 128) {
    int r = tid;
    int pos = (r < 64) ? (c * 64 + r) : (((c + 511) & 511) * 64 + (r - 64));
    int item = sorted[(size_t)bh * 32768 + pos];
    tv[r] = item & 4095;
    if (r < 64) items[r] = item;
  }
  __syncthreads();

  int w = tid >> 6;
  int l = tid & 63;
  int col = l & 15;
  int kg = l >> 4;
  int rq = w * 16 + col;
  int rqx7 = rq & 7, rqx15 = rq & 15;
  int tq = tv[rq];
  float nqv = nq[(size_t)bh * 4096 + tq];   // issued early, hides under gather

  // ---- step 2a: gather K/Q rows -> kf (pure fp16 copy) ----
  {
    int r = tid >> 1, half = tid & 1;
    int t = tv[r];
    const f16x8* src = (const f16x8*)(qk16n + ((size_t)(bh * 4096 + t)) * 64 + half * 32);
    f16x8 d0 = src[0], d1 = src[1], d2 = src[2], d3 = src[3];
    int rx = r & 7, s0 = half * 4;
    *(f16x8*)&kf[r * 64 + (((s0 + 0) ^ rx) << 3)] = d0;
    *(f16x8*)&kf[r * 64 + (((s0 + 1) ^ rx) << 3)] = d1;
    *(f16x8*)&kf[r * 64 + (((s0 + 2) ^ rx) << 3)] = d2;
    *(f16x8*)&kf[r * 64 + (((s0 + 3) ^ rx) << 3)] = d3;
  }

  // ---- step 2b: gather V -> vt (transposed via v_perm) ----
  {
    int jp = tid & 63, db = tid >> 6, f0 = db * 16;
    int t0 = tv[2 * jp], t1 = tv[2 * jp + 1];
    const u32x4* s0p = (const u32x4*)(v16 + ((size_t)(bh * 4096 + t0)) * 64 + f0);
    const u32x4* s1p = (const u32x4*)(v16 + ((size_t)(bh * 4096 + t1)) * 64 + f0);
    u32x4 lo0 = s0p[0], hi0 = s0p[1];
    u32x4 lo1 = s1p[0], hi1 = s1p[1];
    int jbase = ((jp >> 2) /*slot*/);
    int joff = (jp & 3) << 1;
#pragma unroll
    for (int i = 0; i < 16; ++i) {
      int d = f0 + i;
      unsigned a = (i < 8) ? lo0[(i >> 1) & 3] : hi0[(i >> 1) & 3];
      unsigned bsrc = (i < 8) ? lo1[(i >> 1) & 3] : hi1[(i >> 1) & 3];
      unsigned sel = (i & 1) ? 0x07060302u : 0x05040100u;
      unsigned pack = __builtin_amdgcn_perm(bsrc, a, sel);
      *(unsigned*)&vt[d * 128 + ((jbase ^ (d & 15)) << 3) + joff] = pack;
    }
  }
  __syncthreads();

  // ---- step 3: dots S^T = K̂ * Q̂^T (fp16) ----
  f16x8 qf[2];
#pragma unroll
  for (int ks = 0; ks < 2; ++ks)
    qf[ks] = *(f16x8*)&kf[rq * 64 + (((ks * 4 + kg) ^ rqx7) << 3)];

  f32x4 S[8];
#pragma unroll
  for (int mt = 0; mt < 8; ++mt) S[mt] = (f32x4){0.f, 0.f, 0.f, 0.f};

  __builtin_amdgcn_s_setprio(1);
#pragma unroll
  for (int mt = 0; mt < 8; ++mt) {
    int rj = mt * 16 + col;
    int rjx = rj & 7;
#pragma unroll
    for (int ks = 0; ks < 2; ++ks) {
      f16x8 a = *(f16x8*)&kf[rj * 64 + (((ks * 4 + kg) ^ rjx) << 3)];
      S[mt] = __builtin_amdgcn_mfma_f32_16x16x32_f16(a, qf[ks], S[mt], 0, 0, 0);
    }
  }
  __builtin_amdgcn_s_setprio(0);

  // ---- step 4: scale by |q|*log2e, self-mask, softmax over j ----
  float vals[32];
  float mx = -1e30f;
#pragma unroll
  for (int mt = 0; mt < 8; ++mt) {
    int j0 = mt * 16 + kg * 4;
    int4 tk4 = *(int4*)&tv[j0];
    int tki[4] = {tk4.x, tk4.y, tk4.z, tk4.w};
#pragma unroll
    for (int r = 0; r < 4; ++r) {
      float d = S[mt][r] * nqv;
      if (tki[r] == tq) d = -50000.0f * LOG2E;
      vals[mt * 4 + r] = d;
      mx = fmaxf(mx, d);
    }
  }
  mx = fmaxf(mx, __shfl_xor(mx, 16));
  mx = fmaxf(mx, __shfl_xor(mx, 32));
  float ssum = 0.f;
#pragma unroll
  for (int i = 0; i < 32; ++i) {
    float e = __builtin_amdgcn_exp2f(vals[i] - mx);
    vals[i] = e;
    ssum += e;
  }
  ssum += __shfl_xor(ssum, 16);
  ssum += __shfl_xor(ssum, 32);
  if (kg == 0) {
    int item = items[rq];
    lse_buf[(size_t)(bh * 8 + (item >> 12)) * 4096 + (item & 4095)] =
        (mx + __builtin_amdgcn_logf(ssum)) * LN2;
    pinv_s[rq] = 1.f / ssum;
  }

  __syncthreads();   // all waves done reading kf as K/Q

  // ---- step 5: write P (fp16, unnormalized) into kf alias ----
  _Float16* Pb = kf;
#pragma unroll
  for (int mt = 0; mt < 8; ++mt) {
    int j0 = mt * 16 + kg * 4;
    int slot = j0 >> 3;
    int off = rq * 128 + ((slot ^ rqx15) << 3) + ((kg & 1) << 2);
    f16x4 pk;
#pragma unroll
    for (int r = 0; r < 4; ++r) pk[r] = (_Float16)vals[mt * 4 + r];
    *(f16x4*)&Pb[off] = pk;
  }
  asm volatile("s_waitcnt lgkmcnt(0)" ::: "memory");

  // ---- step 6: PV = P * V ----
  f32x4 O[4];
#pragma unroll
  for (int nt = 0; nt < 4; ++nt) O[nt] = (f32x4){0.f, 0.f, 0.f, 0.f};
  __builtin_amdgcn_s_setprio(1);
#pragma unroll
  for (int ks = 0; ks < 4; ++ks) {
    int slot = (ks << 2) + kg;
    f16x8 pa = *(f16x8*)&Pb[rq * 128 + ((slot ^ rqx15) << 3)];
#pragma unroll
    for (int nt = 0; nt < 4; ++nt) {
      int dD = nt * 16 + col;
      f16x8 vb = *(f16x8*)&vt[dD * 128 + ((slot ^ (dD & 15)) << 3)];
      O[nt] = __builtin_amdgcn_mfma_f32_16x16x32_f16(pa, vb, O[nt], 0, 0, 0);
    }
  }
  __builtin_amdgcn_s_setprio(0);

  // ---- step 7: scale by 1/sum, scatter O (fp16) ----
  {
    int i0 = w * 16 + kg * 4;
    int4 it4 = *(int4*)&items[i0];
    float4 pv4 = *(float4*)&pinv_s[i0];
    int iti[4] = {it4.x, it4.y, it4.z, it4.w};
    float pvi[4] = {pv4.x, pv4.y, pv4.z, pv4.w};
#pragma unroll
    for (int r = 0; r < 4; ++r) {
      int item = iti[r];
      _Float16* orow = o_buf + ((size_t)((bh * 8 + (item >> 12)) * 4096 + (item & 4095))) * 64;
#pragma unroll
      for (int nt = 0; nt < 4; ++nt) orow[nt * 16 + col] = (_Float16)(O[nt][r] * pvi[r]);
    }
  }
}

// ============================================================
// K4: combine 8 hash rounds (unchanged)
// ============================================================
__global__ __launch_bounds__(256) void k_combine(const _Float16* __restrict__ o_buf,
                                                 const float* __restrict__ lse_buf,
                                                 float* __restrict__ out) {
  int gid = blockIdx.x * 256 + threadIdx.x;  // < 16*4096*16
  int d4 = gid & 15;
  int t  = (gid >> 4) & 4095;
  int bh = gid >> 16;

  float lx[8];
#pragma unroll
  for (int h = 0; h < 8; ++h) lx[h] = lse_buf[(size_t)(bh * 8 + h) * 4096 + t];
  float m = lx[0];
#pragma unroll
  for (int h = 1; h < 8; ++h) m = fmaxf(m, lx[h]);
  float wv[8]; float s = 0.f;
#pragma unroll
  for (int h = 0; h < 8; ++h) { wv[h] = __expf(lx[h] - m); s += wv[h]; }
  float inv = 1.f / s;

  float ax = 0.f, ay = 0.f, az = 0.f, aw = 0.f;
#pragma unroll
  for (int h = 0; h < 8; ++h) {
    f16x4 ov = *(const f16x4*)(o_buf +
        ((size_t)((bh * 8 + h) * 4096 + t)) * 64 + d4 * 4);
    ax = fmaf(wv[h], (float)ov[0], ax);
    ay = fmaf(wv[h], (float)ov[1], ay);
    az = fmaf(wv[h], (float)ov[2], az);
    aw = fmaf(wv[h], (float)ov[3], aw);
  }
  *(float4*)(out + ((size_t)(bh * 4096 + t)) * 64 + d4 * 4) =
      make_float4(ax * inv, ay * inv, az * inv, aw * inv);
}

// ============================================================
extern "C" void kernel_launch(void* const* d_in, const int* in_sizes, int n_in,
                              void* d_out, int out_size, void* d_ws, size_t ws_size,
                              hipStream_t stream) {
  const float* qk  = (const float*)d_in[0];
  // d_in[1] ("k") is unused by the reference
  const float* vin = (const float*)d_in[2];
  const float* rot = (const float*)d_in[3];

  uint8_t* ws = (uint8_t*)d_ws;
  uint8_t*  buckets = ws + WS_BUCKETS;
  int*      counts  = (int*)(ws + WS_STARTS);
  int*      sorted  = (int*)(ws + WS_SORTED);
  float*    lse_buf = (float*)(ws + WS_LSE);
  _Float16* o_buf   = (_Float16*)(ws + WS_O);
  _Float16* qk16n   = (_Float16*)(ws + WS_QK16);
  _Float16* v16     = (_Float16*)(ws + WS_V16);
  float*    nqbuf   = (float*)(ws + WS_NQ);
  float*    out     = (float*)d_out;

  hipMemsetAsync(counts, 0, BHN * GBUCK * sizeof(int), stream);
  k_prep<<<8192, 128, 0, stream>>>(qk, vin, qk16n, v16, nqbuf);
  k_hash<<<512, 256, 0, stream>>>(qk, rot, buckets, counts);
  k_scan<<<BHN, 512, 0, stream>>>(counts);
  k_rank<<<BHN * NHASH, 64, 0, stream>>>(buckets, counts, sorted);
  k_attn<<<BHN * NCHUNK, 256, 0, stream>>>(qk16n, v16, nqbuf, sorted, o_buf, lse_buf);
  k_combine<<<4096, 256, 0, stream>>>(o_buf, lse_buf, out);
}

// Round 10
// 182.206 us; speedup vs baseline: 1.2007x; 1.2007x over previous
//
#include <hip/hip_runtime.h>
#include <stdint.h>

// ---------------- problem constants ----------------
#define BHN 16          // b*h flat batch
#define TLEN 4096
#define EDIM 64
#define NHASH 8
#define NBUCK 64
#define GBUCK 512
#define NCHUNK 512
#define NITEMS 32768

// ---------------- workspace layout (bytes) ----------------
#define WS_BUCKETS 0u                 // 16*8*4096 u8          = 524288
#define WS_STARTS  524288u            // 16*512 int            = 32768
#define WS_SORTED  557056u            // 16*32768 int          = 2097152
#define WS_LSE     2654208u           // 16*8*4096 f32         = 2097152
#define WS_O       4751360u           // 16*8*4096*64 fp16     = 67108864
#define WS_QK16    71860224u          // 16*4096*64 fp16       = 8388608
#define WS_V16     80248832u          // 16*4096*64 fp16       = 8388608
#define WS_NQ      88637440u          // 16*4096 f32           = 262144
#define WS_QSH     88899584u          // 16*4096*64 fp16       = 8388608
#define WS_QSM     97288192u          // 16*4096*64 fp16       = 8388608
#define WS_QSL     105676800u         // 16*4096*64 fp16       = 8388608
#define WS_RTH     114065408u         // 256*64 fp16           = 32768
#define WS_RTM     114098176u         // 256*64 fp16           = 32768
#define WS_RTL     114130944u         // 256*64 fp16           = 32768
// end ~114.2 MB

typedef __attribute__((ext_vector_type(4))) float f32x4;
typedef __attribute__((ext_vector_type(8))) _Float16 f16x8;     // MFMA A/B frag
typedef __attribute__((ext_vector_type(4))) _Float16 f16x4;
typedef __attribute__((ext_vector_type(4))) unsigned u32x4;

#define LOG2E 1.44269504088896f
#define LN2   0.69314718055995f
#define S11   4.8828125e-4f            // 2^-11
#define S22   2.384185791015625e-7f    // 2^-22

// exact fp16 triple split: x = h + m*2^-11 + l*2^-22 (+ ~2^-33 residual).
// m,l stored PRE-SCALED into fp16 normal range (no subnormal flush risk).
static __device__ __forceinline__ void split3(float x, _Float16& h0, _Float16& m0, _Float16& l0) {
  h0 = (_Float16)x;
  float r1 = x - (float)h0;                 // exact (Sterbenz)
  m0 = (_Float16)(r1 * 2048.0f);            // scaled 2^11, exact pow2 scale
  float r2 = r1 - (float)m0 * (1.0f / 2048.0f);  // exact
  l0 = (_Float16)(r2 * 4194304.0f);         // scaled 2^22
}

// ============================================================
// K0: prep — normalize qk rows to fp16 + |q|*log2e + v fp16,
// and emit the exact fp16 triple-split of raw qk for the
// MFMA-based LSH hash.
// ============================================================
__global__ __launch_bounds__(128) void k_prep(const float* __restrict__ qk,
                                              const float* __restrict__ vin,
                                              _Float16* __restrict__ qk16n,
                                              _Float16* __restrict__ v16,
                                              float* __restrict__ nq,
                                              _Float16* __restrict__ qsh,
                                              _Float16* __restrict__ qsm,
                                              _Float16* __restrict__ qsl) {
  int blk = blockIdx.x;             // 8192 = b*4096 + t
  int b = blk >> 12, t = blk & 4095;
  int tid = threadIdx.x;
  int h = tid >> 4, e4 = tid & 15;

  size_t in_base = ((size_t)((b * 4096 + t) * 8 + h)) * 64 + e4 * 4;
  float4 qv = *(const float4*)(qk + in_base);
  float ss = qv.x * qv.x + qv.y * qv.y + qv.z * qv.z + qv.w * qv.w;
  ss += __shfl_xor(ss, 1);
  ss += __shfl_xor(ss, 2);
  ss += __shfl_xor(ss, 4);
  ss += __shfl_xor(ss, 8);
  float nrm = fmaxf(sqrtf(ss), 1e-12f);
  float inv = 1.f / nrm;

  size_t out_base = ((size_t)((b * 8 + h) * 4096 + t)) * 64 + e4 * 4;
  f16x4 qh;
  qh[0] = (_Float16)(qv.x * inv); qh[1] = (_Float16)(qv.y * inv);
  qh[2] = (_Float16)(qv.z * inv); qh[3] = (_Float16)(qv.w * inv);
  *(f16x4*)(qk16n + out_base) = qh;
  if (e4 == 0) nq[(size_t)(b * 8 + h) * 4096 + t] = nrm * LOG2E;

  // triple-split of raw q for the hash GEMM (locals -> vector assign;
  // references can't bind to ext_vector elements)
  {
    float xs[4] = {qv.x, qv.y, qv.z, qv.w};
    f16x4 sh_, sm_, sl_;
#pragma unroll
    for (int i = 0; i < 4; ++i) {
      _Float16 h0, m0, l0;
      split3(xs[i], h0, m0, l0);
      sh_[i] = h0; sm_[i] = m0; sl_[i] = l0;
    }
    *(f16x4*)(qsh + out_base) = sh_;
    *(f16x4*)(qsm + out_base) = sm_;
    *(f16x4*)(qsl + out_base) = sl_;
  }

  float4 vv = *(const float4*)(vin + in_base);
  f16x4 vh;
  vh[0] = (_Float16)vv.x; vh[1] = (_Float16)vv.y;
  vh[2] = (_Float16)vv.z; vh[3] = (_Float16)vv.w;
  *(f16x4*)(v16 + out_base) = vh;
}

// ============================================================
// K0b: transpose + triple-split rotations: rt*[n=256][f=64].
// rot layout: [f=64][h*32+i = 256]; coalesced reads across n.
// ============================================================
__global__ __launch_bounds__(256) void k_rotsplit(const float* __restrict__ rot,
                                                  _Float16* __restrict__ rth,
                                                  _Float16* __restrict__ rtm,
                                                  _Float16* __restrict__ rtl) {
  int n = threadIdx.x;
  for (int f = 0; f < 64; ++f) {
    float x = rot[f * 256 + n];
    _Float16 h0, m0, l0;
    split3(x, h0, m0, l0);
    rth[n * 64 + f] = h0;
    rtm[n * 64 + f] = m0;
    rtl[n * 64 + f] = l0;
  }
}

// ============================================================
// K1: LSH hash via MFMA (exact fp16 triple-split GEMM).
// block = (bh, 64-token tile); 4 waves; wave w -> buckets
// cols [w*64, w*64+64) = hashes 2w, 2w+1.
// A = token rows (LDS, swizzled), B = rotT rows (global, hot).
// D[m=token][n=bucket]: col=lane&15, row=(lane>>4)*4+reg.
// V = C0 + C1*2^-11 + C2*2^-22; argmax over [V, -V] with
// first-index semantics via (|V|, signed index) comparator.
// ============================================================
__global__ __launch_bounds__(256) void k_hash2(const _Float16* __restrict__ qsh,
                                               const _Float16* __restrict__ qsm,
                                               const _Float16* __restrict__ qsl,
                                               const _Float16* __restrict__ rth,
                                               const _Float16* __restrict__ rtm,
                                               const _Float16* __restrict__ rtl,
                                               uint8_t* __restrict__ buckets,
                                               int* __restrict__ counts) {
  __shared__ __attribute__((aligned(16))) _Float16 ah[64 * 64];
  __shared__ __attribute__((aligned(16))) _Float16 am[64 * 64];
  __shared__ __attribute__((aligned(16))) _Float16 al[64 * 64];

  int tid = threadIdx.x;
  int bh = blockIdx.x >> 6;
  int tt = blockIdx.x & 63;

  // ---- stage A (64 tokens x 64 f, 3 levels) ----
  {
    int r = tid & 63, fq = tid >> 6;          // fq: 16 f's each
    size_t g = ((size_t)(bh * 4096 + tt * 64 + r)) * 64 + fq * 16;
    int s0 = fq * 2, rx = r & 7;
    f16x8 x0 = *(const f16x8*)(qsh + g), x1 = *(const f16x8*)(qsh + g + 8);
    *(f16x8*)&ah[r * 64 + ((s0 ^ rx) << 3)] = x0;
    *(f16x8*)&ah[r * 64 + (((s0 + 1) ^ rx) << 3)] = x1;
    f16x8 y0 = *(const f16x8*)(qsm + g), y1 = *(const f16x8*)(qsm + g + 8);
    *(f16x8*)&am[r * 64 + ((s0 ^ rx) << 3)] = y0;
    *(f16x8*)&am[r * 64 + (((s0 + 1) ^ rx) << 3)] = y1;
    f16x8 z0 = *(const f16x8*)(qsl + g), z1 = *(const f16x8*)(qsl + g + 8);
    *(f16x8*)&al[r * 64 + ((s0 ^ rx) << 3)] = z0;
    *(f16x8*)&al[r * 64 + (((s0 + 1) ^ rx) << 3)] = z1;
  }
  __syncthreads();

  int w = tid >> 6, l = tid & 63;
  int col = l & 15, kg = l >> 4;

  float bv[4][4];
  int   bi[4][4];

#pragma unroll
  for (int nt = 0; nt < 4; ++nt) {
    // B frags: 3 levels x 2 k-halves, from global (L1/L2-hot 96 KB total)
    int nrow = w * 64 + nt * 16 + col;
    const _Float16* bh_p = rth + nrow * 64 + kg * 8;
    const _Float16* bm_p = rtm + nrow * 64 + kg * 8;
    const _Float16* bl_p = rtl + nrow * 64 + kg * 8;
    f16x8 Bh0 = *(const f16x8*)(bh_p),      Bh1 = *(const f16x8*)(bh_p + 32);
    f16x8 Bm0 = *(const f16x8*)(bm_p),      Bm1 = *(const f16x8*)(bm_p + 32);
    f16x8 Bl0 = *(const f16x8*)(bl_p),      Bl1 = *(const f16x8*)(bl_p + 32);

    f32x4 C0[4], C1[4], C2[4];
#pragma unroll
    for (int mt = 0; mt < 4; ++mt) {
      C0[mt] = (f32x4){0.f, 0.f, 0.f, 0.f};
      C1[mt] = (f32x4){0.f, 0.f, 0.f, 0.f};
      C2[mt] = (f32x4){0.f, 0.f, 0.f, 0.f};
    }

    __builtin_amdgcn_s_setprio(1);
#pragma unroll
    for (int mt = 0; mt < 4; ++mt) {
      int ar = mt * 16 + col, arx = ar & 7;
#pragma unroll
      for (int kh = 0; kh < 2; ++kh) {
        int slot = kh * 4 + kg;
        f16x8 Ah = *(f16x8*)&ah[ar * 64 + ((slot ^ arx) << 3)];
        f16x8 Am = *(f16x8*)&am[ar * 64 + ((slot ^ arx) << 3)];
        f16x8 Al = *(f16x8*)&al[ar * 64 + ((slot ^ arx) << 3)];
        f16x8 Bh = kh ? Bh1 : Bh0;
        f16x8 Bm = kh ? Bm1 : Bm0;
        f16x8 Bl = kh ? Bl1 : Bl0;
        C2[mt] = __builtin_amdgcn_mfma_f32_16x16x32_f16(Ah, Bl, C2[mt], 0, 0, 0);
        C2[mt] = __builtin_amdgcn_mfma_f32_16x16x32_f16(Al, Bh, C2[mt], 0, 0, 0);
        C2[mt] = __builtin_amdgcn_mfma_f32_16x16x32_f16(Am, Bm, C2[mt], 0, 0, 0);
        C1[mt] = __builtin_amdgcn_mfma_f32_16x16x32_f16(Ah, Bm, C1[mt], 0, 0, 0);
        C1[mt] = __builtin_amdgcn_mfma_f32_16x16x32_f16(Am, Bh, C1[mt], 0, 0, 0);
        C0[mt] = __builtin_amdgcn_mfma_f32_16x16x32_f16(Ah, Bh, C0[mt], 0, 0, 0);
      }
    }
    __builtin_amdgcn_s_setprio(0);

    // combine levels + fold argmax candidates (|V|, signed idx)
    int ib = (nt & 1) * 16 + col;
#pragma unroll
    for (int mt = 0; mt < 4; ++mt) {
#pragma unroll
      for (int r = 0; r < 4; ++r) {
        float V = C0[mt][r] + C1[mt][r] * S11 + C2[mt][r] * S22;
        float av = fabsf(V);
        int fi = (V >= 0.f) ? ib : ib + 32;   // V==0 -> +side (lower idx)
        if ((nt & 1) == 0) {
          bv[mt][r] = av; bi[mt][r] = fi;
        } else {
          if (av > bv[mt][r] || (av == bv[mt][r] && fi < bi[mt][r])) {
            bv[mt][r] = av; bi[mt][r] = fi;
          }
        }
      }
    }

    // end of hash (odd nt): reduce across 16 lanes, write
    if (nt & 1) {
      int h = w * 2 + (nt >> 1);
#pragma unroll
      for (int mt = 0; mt < 4; ++mt) {
#pragma unroll
        for (int r = 0; r < 4; ++r) {
          float v = bv[mt][r]; int i_ = bi[mt][r];
#pragma unroll
          for (int d = 1; d < 16; d <<= 1) {
            float ov = __shfl_xor(v, d);
            int   oi = __shfl_xor(i_, d);
            if (ov > v || (ov == v && oi < i_)) { v = ov; i_ = oi; }
          }
          if (col == 0) {
            int t = tt * 64 + mt * 16 + kg * 4 + r;
            buckets[(bh * 8 + h) * 4096 + t] = (uint8_t)i_;
            atomicAdd(&counts[bh * 512 + h * 64 + i_], 1);
          }
        }
      }
    }
  }
}

// ============================================================
// K2a: exclusive scan (unchanged)
// ============================================================
__global__ __launch_bounds__(512) void k_scan(int* __restrict__ counts) {
  __shared__ int s[512];
  int tid = threadIdx.x;
  int bh = blockIdx.x;
  s[tid] = counts[bh * 512 + tid];
  __syncthreads();
#pragma unroll
  for (int off = 1; off < 512; off <<= 1) {
    int v = (tid >= off) ? s[tid - off] : 0;
    __syncthreads();
    s[tid] += v;
    __syncthreads();
  }
  counts[bh * 512 + tid] = (tid == 0) ? 0 : s[tid - 1];
}

// ============================================================
// K2b: stable rank + scatter (unchanged)
// ============================================================
__global__ __launch_bounds__(64) void k_rank(const uint8_t* __restrict__ buckets,
                                             const int* __restrict__ starts,
                                             int* __restrict__ sorted) {
  __shared__ uint8_t bkt[4096];
  __shared__ uint8_t lrk[4096];
  __shared__ int hist[64 * 65];
  __shared__ int sbase[64];
  int tid = threadIdx.x;
  int bh = blockIdx.x >> 3, h = blockIdx.x & 7;

  const int* src = (const int*)(buckets + (size_t)(bh * 8 + h) * 4096);
  for (int k = tid; k < 1024; k += 64) ((int*)bkt)[k] = src[k];
  sbase[tid] = starts[bh * 512 + h * 64 + tid];
  for (int k = tid; k < 64 * 65; k += 64) hist[k] = 0;
  __syncthreads();

  {
    int c = tid;
    for (int k = 0; k < 64; ++k) {
      int t = c * 64 + k;
      int bin = bkt[t];
      int r = hist[c * 65 + bin];
      hist[c * 65 + bin] = r + 1;
      lrk[t] = (uint8_t)r;
    }
  }
  __syncthreads();
  {
    int bb = tid; int run = 0;
    for (int c2 = 0; c2 < 64; ++c2) {
      int val = hist[c2 * 65 + bb];
      hist[c2 * 65 + bb] = run;
      run += val;
    }
  }
  __syncthreads();
  {
    int c = tid;
    int* dst = sorted + (size_t)bh * 32768;
    for (int k = 0; k < 64; ++k) {
      int t = c * 64 + k;
      int bin = bkt[t];
      int pos = sbase[bin] + hist[c * 65 + bin] + (int)lrk[t];
      dst[pos] = h * 4096 + t;
    }
  }
}

// ============================================================
// K3: chunked attention, fp16 MFMA (unchanged from round 5)
// ============================================================
__global__ __launch_bounds__(256, 4) void k_attn(const _Float16* __restrict__ qk16n,
                                                 const _Float16* __restrict__ v16,
                                                 const float* __restrict__ nq,
                                                 const int* __restrict__ sorted,
                                                 _Float16* __restrict__ o_buf,
                                                 float* __restrict__ lse_buf) {
  __shared__ __attribute__((aligned(16))) _Float16 kf[128 * 64];
  __shared__ __attribute__((aligned(16))) _Float16 vt[64 * 128];
  __shared__ __attribute__((aligned(16))) float pinv_s[64];
  __shared__ __attribute__((aligned(16))) int tv[128];
  __shared__ __attribute__((aligned(16))) int items[64];

  int tid = threadIdx.x;
  int bh = blockIdx.x >> 9;
  int c  = blockIdx.x & 511;

  // ---- step 1: item ids for 64 current + 64 look-back rows ----
  if (tid < 128) {
    int r = tid;
    int pos = (r < 64) ? (c * 64 + r) : (((c + 511) & 511) * 64 + (r - 64));
    int item = sorted[(size_t)bh * 32768 + pos];
    tv[r] = item & 4095;
    if (r < 64) items[r] = item;
  }
  __syncthreads();

  int w = tid >> 6;
  int l = tid & 63;
  int col = l & 15;
  int kg = l >> 4;
  int rq = w * 16 + col;
  int rqx7 = rq & 7, rqx15 = rq & 15;
  int tq = tv[rq];
  float nqv = nq[(size_t)bh * 4096 + tq];   // issued early, hides under gather

  // ---- step 2a: gather K/Q rows -> kf (pure fp16 copy) ----
  {
    int r = tid >> 1, half = tid & 1;
    int t = tv[r];
    const f16x8* src = (const f16x8*)(qk16n + ((size_t)(bh * 4096 + t)) * 64 + half * 32);
    f16x8 d0 = src[0], d1 = src[1], d2 = src[2], d3 = src[3];
    int rx = r & 7, s0 = half * 4;
    *(f16x8*)&kf[r * 64 + (((s0 + 0) ^ rx) << 3)] = d0;
    *(f16x8*)&kf[r * 64 + (((s0 + 1) ^ rx) << 3)] = d1;
    *(f16x8*)&kf[r * 64 + (((s0 + 2) ^ rx) << 3)] = d2;
    *(f16x8*)&kf[r * 64 + (((s0 + 3) ^ rx) << 3)] = d3;
  }

  // ---- step 2b: gather V -> vt (transposed via v_perm) ----
  {
    int jp = tid & 63, db = tid >> 6, f0 = db * 16;
    int t0 = tv[2 * jp], t1 = tv[2 * jp + 1];
    const u32x4* s0p = (const u32x4*)(v16 + ((size_t)(bh * 4096 + t0)) * 64 + f0);
    const u32x4* s1p = (const u32x4*)(v16 + ((size_t)(bh * 4096 + t1)) * 64 + f0);
    u32x4 lo0 = s0p[0], hi0 = s0p[1];
    u32x4 lo1 = s1p[0], hi1 = s1p[1];
    int jbase = ((jp >> 2) /*slot*/);
    int joff = (jp & 3) << 1;
#pragma unroll
    for (int i = 0; i < 16; ++i) {
      int d = f0 + i;
      unsigned a = (i < 8) ? lo0[(i >> 1) & 3] : hi0[(i >> 1) & 3];
      unsigned bsrc = (i < 8) ? lo1[(i >> 1) & 3] : hi1[(i >> 1) & 3];
      unsigned sel = (i & 1) ? 0x07060302u : 0x05040100u;
      unsigned pack = __builtin_amdgcn_perm(bsrc, a, sel);
      *(unsigned*)&vt[d * 128 + ((jbase ^ (d & 15)) << 3) + joff] = pack;
    }
  }
  __syncthreads();

  // ---- step 3: dots S^T = K̂ * Q̂^T (fp16) ----
  f16x8 qf[2];
#pragma unroll
  for (int ks = 0; ks < 2; ++ks)
    qf[ks] = *(f16x8*)&kf[rq * 64 + (((ks * 4 + kg) ^ rqx7) << 3)];

  f32x4 S[8];
#pragma unroll
  for (int mt = 0; mt < 8; ++mt) S[mt] = (f32x4){0.f, 0.f, 0.f, 0.f};

  __builtin_amdgcn_s_setprio(1);
#pragma unroll
  for (int mt = 0; mt < 8; ++mt) {
    int rj = mt * 16 + col;
    int rjx = rj & 7;
#pragma unroll
    for (int ks = 0; ks < 2; ++ks) {
      f16x8 a = *(f16x8*)&kf[rj * 64 + (((ks * 4 + kg) ^ rjx) << 3)];
      S[mt] = __builtin_amdgcn_mfma_f32_16x16x32_f16(a, qf[ks], S[mt], 0, 0, 0);
    }
  }
  __builtin_amdgcn_s_setprio(0);

  // ---- step 4: scale by |q|*log2e, self-mask, softmax over j ----
  float vals[32];
  float mx = -1e30f;
#pragma unroll
  for (int mt = 0; mt < 8; ++mt) {
    int j0 = mt * 16 + kg * 4;
    int4 tk4 = *(int4*)&tv[j0];
    int tki[4] = {tk4.x, tk4.y, tk4.z, tk4.w};
#pragma unroll
    for (int r = 0; r < 4; ++r) {
      float d = S[mt][r] * nqv;
      if (tki[r] == tq) d = -50000.0f * LOG2E;
      vals[mt * 4 + r] = d;
      mx = fmaxf(mx, d);
    }
  }
  mx = fmaxf(mx, __shfl_xor(mx, 16));
  mx = fmaxf(mx, __shfl_xor(mx, 32));
  float ssum = 0.f;
#pragma unroll
  for (int i = 0; i < 32; ++i) {
    float e = __builtin_amdgcn_exp2f(vals[i] - mx);
    vals[i] = e;
    ssum += e;
  }
  ssum += __shfl_xor(ssum, 16);
  ssum += __shfl_xor(ssum, 32);
  if (kg == 0) {
    int item = items[rq];
    lse_buf[(size_t)(bh * 8 + (item >> 12)) * 4096 + (item & 4095)] =
        (mx + __builtin_amdgcn_logf(ssum)) * LN2;
    pinv_s[rq] = 1.f / ssum;
  }

  __syncthreads();   // all waves done reading kf as K/Q

  // ---- step 5: write P (fp16, unnormalized) into kf alias ----
  _Float16* Pb = kf;
#pragma unroll
  for (int mt = 0; mt < 8; ++mt) {
    int j0 = mt * 16 + kg * 4;
    int slot = j0 >> 3;
    int off = rq * 128 + ((slot ^ rqx15) << 3) + ((kg & 1) << 2);
    f16x4 pk;
#pragma unroll
    for (int r = 0; r < 4; ++r) pk[r] = (_Float16)vals[mt * 4 + r];
    *(f16x4*)&Pb[off] = pk;
  }
  asm volatile("s_waitcnt lgkmcnt(0)" ::: "memory");

  // ---- step 6: PV = P * V ----
  f32x4 O[4];
#pragma unroll
  for (int nt = 0; nt < 4; ++nt) O[nt] = (f32x4){0.f, 0.f, 0.f, 0.f};
  __builtin_amdgcn_s_setprio(1);
#pragma unroll
  for (int ks = 0; ks < 4; ++ks) {
    int slot = (ks << 2) + kg;
    f16x8 pa = *(f16x8*)&Pb[rq * 128 + ((slot ^ rqx15) << 3)];
#pragma unroll
    for (int nt = 0; nt < 4; ++nt) {
      int dD = nt * 16 + col;
      f16x8 vb = *(f16x8*)&vt[dD * 128 + ((slot ^ (dD & 15)) << 3)];
      O[nt] = __builtin_amdgcn_mfma_f32_16x16x32_f16(pa, vb, O[nt], 0, 0, 0);
    }
  }
  __builtin_amdgcn_s_setprio(0);

  // ---- step 7: scale by 1/sum, scatter O (fp16) ----
  {
    int i0 = w * 16 + kg * 4;
    int4 it4 = *(int4*)&items[i0];
    float4 pv4 = *(float4*)&pinv_s[i0];
    int iti[4] = {it4.x, it4.y, it4.z, it4.w};
    float pvi[4] = {pv4.x, pv4.y, pv4.z, pv4.w};
#pragma unroll
    for (int r = 0; r < 4; ++r) {
      int item = iti[r];
      _Float16* orow = o_buf + ((size_t)((bh * 8 + (item >> 12)) * 4096 + (item & 4095))) * 64;
#pragma unroll
      for (int nt = 0; nt < 4; ++nt) orow[nt * 16 + col] = (_Float16)(O[nt][r] * pvi[r]);
    }
  }
}

// ============================================================
// K4: combine 8 hash rounds (unchanged)
// ============================================================
__global__ __launch_bounds__(256) void k_combine(const _Float16* __restrict__ o_buf,
                                                 const float* __restrict__ lse_buf,
                                                 float* __restrict__ out) {
  int gid = blockIdx.x * 256 + threadIdx.x;  // < 16*4096*16
  int d4 = gid & 15;
  int t  = (gid >> 4) & 4095;
  int bh = gid >> 16;

  float lx[8];
#pragma unroll
  for (int h = 0; h < 8; ++h) lx[h] = lse_buf[(size_t)(bh * 8 + h) * 4096 + t];
  float m = lx[0];
#pragma unroll
  for (int h = 1; h < 8; ++h) m = fmaxf(m, lx[h]);
  float wv[8]; float s = 0.f;
#pragma unroll
  for (int h = 0; h < 8; ++h) { wv[h] = __expf(lx[h] - m); s += wv[h]; }
  float inv = 1.f / s;

  float ax = 0.f, ay = 0.f, az = 0.f, aw = 0.f;
#pragma unroll
  for (int h = 0; h < 8; ++h) {
    f16x4 ov = *(const f16x4*)(o_buf +
        ((size_t)((bh * 8 + h) * 4096 + t)) * 64 + d4 * 4);
    ax = fmaf(wv[h], (float)ov[0], ax);
    ay = fmaf(wv[h], (float)ov[1], ay);
    az = fmaf(wv[h], (float)ov[2], az);
    aw = fmaf(wv[h], (float)ov[3], aw);
  }
  *(float4*)(out + ((size_t)(bh * 4096 + t)) * 64 + d4 * 4) =
      make_float4(ax * inv, ay * inv, az * inv, aw * inv);
}

// ============================================================
extern "C" void kernel_launch(void* const* d_in, const int* in_sizes, int n_in,
                              void* d_out, int out_size, void* d_ws, size_t ws_size,
                              hipStream_t stream) {
  const float* qk  = (const float*)d_in[0];
  // d_in[1] ("k") is unused by the reference
  const float* vin = (const float*)d_in[2];
  const float* rot = (const float*)d_in[3];

  uint8_t* ws = (uint8_t*)d_ws;
  uint8_t*  buckets = ws + WS_BUCKETS;
  int*      counts  = (int*)(ws + WS_STARTS);
  int*      sorted  = (int*)(ws + WS_SORTED);
  float*    lse_buf = (float*)(ws + WS_LSE);
  _Float16* o_buf   = (_Float16*)(ws + WS_O);
  _Float16* qk16n   = (_Float16*)(ws + WS_QK16);
  _Float16* v16     = (_Float16*)(ws + WS_V16);
  float*    nqbuf   = (float*)(ws + WS_NQ);
  _Float16* qsh     = (_Float16*)(ws + WS_QSH);
  _Float16* qsm     = (_Float16*)(ws + WS_QSM);
  _Float16* qsl     = (_Float16*)(ws + WS_QSL);
  _Float16* rth     = (_Float16*)(ws + WS_RTH);
  _Float16* rtm     = (_Float16*)(ws + WS_RTM);
  _Float16* rtl     = (_Float16*)(ws + WS_RTL);
  float*    out     = (float*)d_out;

  (void)hipMemsetAsync(counts, 0, BHN * GBUCK * sizeof(int), stream);
  k_rotsplit<<<1, 256, 0, stream>>>(rot, rth, rtm, rtl);
  k_prep<<<8192, 128, 0, stream>>>(qk, vin, qk16n, v16, nqbuf, qsh, qsm, qsl);
  k_hash2<<<BHN * 64, 256, 0, stream>>>(qsh, qsm, qsl, rth, rtm, rtl, buckets, counts);
  k_scan<<<BHN, 512, 0, stream>>>(counts);
  k_rank<<<BHN * NHASH, 64, 0, stream>>>(buckets, counts, sorted);
  k_attn<<<BHN * NCHUNK, 256, 0, stream>>>(qk16n, v16, nqbuf, sorted, o_buf, lse_buf);
  k_combine<<<4096, 256, 0, stream>>>(o_buf, lse_buf, out);
}

// Round 12
// 151.240 us; speedup vs baseline: 1.4465x; 1.2047x over previous
//
#include <hip/hip_runtime.h>
#include <stdint.h>

// ---------------- problem constants ----------------
#define BHN 16          // b*h flat batch
#define TLEN 4096
#define EDIM 64
#define NHASH 8
#define NBUCK 64
#define GBUCK 512
#define NCHUNK 512
#define NITEMS 32768

// ---------------- workspace layout (bytes) ----------------
#define WS_BUCKETS 0u                 // 16*8*4096 u8          = 524288
#define WS_STARTS  524288u            // 16*512 int            = 32768
#define WS_SORTED  557056u            // 16*32768 int          = 2097152
#define WS_LSE     2654208u           // 16*8*4096 f32         = 2097152
#define WS_O       4751360u           // 16*8*4096*64 fp16     = 67108864
#define WS_QK16    71860224u          // 16*4096*64 fp16       = 8388608
#define WS_V16     80248832u          // 16*4096*64 fp16       = 8388608
#define WS_NQ      88637440u          // 16*4096 f32           = 262144
#define WS_QSH     88899584u          // 16*4096*64 fp16       = 8388608
#define WS_QSM     97288192u          // 16*4096*64 fp16       = 8388608
#define WS_QSL     105676800u         // 16*4096*64 fp16       = 8388608
#define WS_RTH     114065408u         // 256*64 fp16           = 32768
#define WS_RTM     114098176u         // 256*64 fp16           = 32768
#define WS_RTL     114130944u         // 256*64 fp16           = 32768
// end ~114.2 MB

typedef __attribute__((ext_vector_type(4))) float f32x4;
typedef __attribute__((ext_vector_type(8))) _Float16 f16x8;     // MFMA A/B frag
typedef __attribute__((ext_vector_type(4))) _Float16 f16x4;
typedef __attribute__((ext_vector_type(4))) unsigned u32x4;

#define LOG2E 1.44269504088896f
#define LN2   0.69314718055995f
#define S11   4.8828125e-4f            // 2^-11
#define S22   2.384185791015625e-7f    // 2^-22

// exact fp16 triple split: x = h + m*2^-11 + l*2^-22 (+ ~2^-33 residual).
static __device__ __forceinline__ void split3(float x, _Float16& h0, _Float16& m0, _Float16& l0) {
  h0 = (_Float16)x;
  float r1 = x - (float)h0;                 // exact (Sterbenz)
  m0 = (_Float16)(r1 * 2048.0f);            // scaled 2^11, exact pow2 scale
  float r2 = r1 - (float)m0 * (1.0f / 2048.0f);  // exact
  l0 = (_Float16)(r2 * 4194304.0f);         // scaled 2^22
}

// ============================================================
// K0: prep — normalize qk rows to fp16 + |q|*log2e + v fp16,
// plus exact fp16 triple-split of raw qk for the MFMA hash.
// ============================================================
__global__ __launch_bounds__(128) void k_prep(const float* __restrict__ qk,
                                              const float* __restrict__ vin,
                                              _Float16* __restrict__ qk16n,
                                              _Float16* __restrict__ v16,
                                              float* __restrict__ nq,
                                              _Float16* __restrict__ qsh,
                                              _Float16* __restrict__ qsm,
                                              _Float16* __restrict__ qsl) {
  int blk = blockIdx.x;             // 8192 = b*4096 + t
  int b = blk >> 12, t = blk & 4095;
  int tid = threadIdx.x;
  int h = tid >> 4, e4 = tid & 15;

  size_t in_base = ((size_t)((b * 4096 + t) * 8 + h)) * 64 + e4 * 4;
  float4 qv = *(const float4*)(qk + in_base);
  float ss = qv.x * qv.x + qv.y * qv.y + qv.z * qv.z + qv.w * qv.w;
  ss += __shfl_xor(ss, 1);
  ss += __shfl_xor(ss, 2);
  ss += __shfl_xor(ss, 4);
  ss += __shfl_xor(ss, 8);
  float nrm = fmaxf(sqrtf(ss), 1e-12f);
  float inv = 1.f / nrm;

  size_t out_base = ((size_t)((b * 8 + h) * 4096 + t)) * 64 + e4 * 4;
  f16x4 qh;
  qh[0] = (_Float16)(qv.x * inv); qh[1] = (_Float16)(qv.y * inv);
  qh[2] = (_Float16)(qv.z * inv); qh[3] = (_Float16)(qv.w * inv);
  *(f16x4*)(qk16n + out_base) = qh;
  if (e4 == 0) nq[(size_t)(b * 8 + h) * 4096 + t] = nrm * LOG2E;

  {
    float xs[4] = {qv.x, qv.y, qv.z, qv.w};
    f16x4 sh_, sm_, sl_;
#pragma unroll
    for (int i = 0; i < 4; ++i) {
      _Float16 h0, m0, l0;
      split3(xs[i], h0, m0, l0);
      sh_[i] = h0; sm_[i] = m0; sl_[i] = l0;
    }
    *(f16x4*)(qsh + out_base) = sh_;
    *(f16x4*)(qsm + out_base) = sm_;
    *(f16x4*)(qsl + out_base) = sl_;
  }

  float4 vv = *(const float4*)(vin + in_base);
  f16x4 vh;
  vh[0] = (_Float16)vv.x; vh[1] = (_Float16)vv.y;
  vh[2] = (_Float16)vv.z; vh[3] = (_Float16)vv.w;
  *(f16x4*)(v16 + out_base) = vh;
}

// ============================================================
// K0b: transpose + triple-split rotations: rt*[n=256][f=64].
// ============================================================
__global__ __launch_bounds__(256) void k_rotsplit(const float* __restrict__ rot,
                                                  _Float16* __restrict__ rth,
                                                  _Float16* __restrict__ rtm,
                                                  _Float16* __restrict__ rtl) {
  int n = threadIdx.x;
  for (int f = 0; f < 64; ++f) {
    float x = rot[f * 256 + n];
    _Float16 h0, m0, l0;
    split3(x, h0, m0, l0);
    rth[n * 64 + f] = h0;
    rtm[n * 64 + f] = m0;
    rtl[n * 64 + f] = l0;
  }
}

// ============================================================
// K1: LSH hash via MFMA — NO GLOBAL ATOMICS (r10 diagnosis:
// 524K device-scope atomicAdds on 32KB counts were the ~70 µs
// floor across all hash implementations; cross-XCD line
// ping-pong). Buckets only; counts rebuilt in k_hist.
// ============================================================
__global__ __launch_bounds__(256) void k_hash2(const _Float16* __restrict__ qsh,
                                               const _Float16* __restrict__ qsm,
                                               const _Float16* __restrict__ qsl,
                                               const _Float16* __restrict__ rth,
                                               const _Float16* __restrict__ rtm,
                                               const _Float16* __restrict__ rtl,
                                               uint8_t* __restrict__ buckets) {
  __shared__ __attribute__((aligned(16))) _Float16 ah[64 * 64];
  __shared__ __attribute__((aligned(16))) _Float16 am[64 * 64];
  __shared__ __attribute__((aligned(16))) _Float16 al[64 * 64];

  int tid = threadIdx.x;
  int bh = blockIdx.x >> 6;
  int tt = blockIdx.x & 63;

  // ---- stage A (64 tokens x 64 f, 3 levels) ----
  {
    int r = tid & 63, fq = tid >> 6;          // fq: 16 f's each
    size_t g = ((size_t)(bh * 4096 + tt * 64 + r)) * 64 + fq * 16;
    int s0 = fq * 2, rx = r & 7;
    f16x8 x0 = *(const f16x8*)(qsh + g), x1 = *(const f16x8*)(qsh + g + 8);
    *(f16x8*)&ah[r * 64 + ((s0 ^ rx) << 3)] = x0;
    *(f16x8*)&ah[r * 64 + (((s0 + 1) ^ rx) << 3)] = x1;
    f16x8 y0 = *(const f16x8*)(qsm + g), y1 = *(const f16x8*)(qsm + g + 8);
    *(f16x8*)&am[r * 64 + ((s0 ^ rx) << 3)] = y0;
    *(f16x8*)&am[r * 64 + (((s0 + 1) ^ rx) << 3)] = y1;
    f16x8 z0 = *(const f16x8*)(qsl + g), z1 = *(const f16x8*)(qsl + g + 8);
    *(f16x8*)&al[r * 64 + ((s0 ^ rx) << 3)] = z0;
    *(f16x8*)&al[r * 64 + (((s0 + 1) ^ rx) << 3)] = z1;
  }
  __syncthreads();

  int w = tid >> 6, l = tid & 63;
  int col = l & 15, kg = l >> 4;

  float bv[4][4];
  int   bi[4][4];

#pragma unroll
  for (int nt = 0; nt < 4; ++nt) {
    int nrow = w * 64 + nt * 16 + col;
    const _Float16* bh_p = rth + nrow * 64 + kg * 8;
    const _Float16* bm_p = rtm + nrow * 64 + kg * 8;
    const _Float16* bl_p = rtl + nrow * 64 + kg * 8;
    f16x8 Bh0 = *(const f16x8*)(bh_p),      Bh1 = *(const f16x8*)(bh_p + 32);
    f16x8 Bm0 = *(const f16x8*)(bm_p),      Bm1 = *(const f16x8*)(bm_p + 32);
    f16x8 Bl0 = *(const f16x8*)(bl_p),      Bl1 = *(const f16x8*)(bl_p + 32);

    f32x4 C0[4], C1[4], C2[4];
#pragma unroll
    for (int mt = 0; mt < 4; ++mt) {
      C0[mt] = (f32x4){0.f, 0.f, 0.f, 0.f};
      C1[mt] = (f32x4){0.f, 0.f, 0.f, 0.f};
      C2[mt] = (f32x4){0.f, 0.f, 0.f, 0.f};
    }

    __builtin_amdgcn_s_setprio(1);
#pragma unroll
    for (int mt = 0; mt < 4; ++mt) {
      int ar = mt * 16 + col, arx = ar & 7;
#pragma unroll
      for (int kh = 0; kh < 2; ++kh) {
        int slot = kh * 4 + kg;
        f16x8 Ah = *(f16x8*)&ah[ar * 64 + ((slot ^ arx) << 3)];
        f16x8 Am = *(f16x8*)&am[ar * 64 + ((slot ^ arx) << 3)];
        f16x8 Al = *(f16x8*)&al[ar * 64 + ((slot ^ arx) << 3)];
        f16x8 Bh = kh ? Bh1 : Bh0;
        f16x8 Bm = kh ? Bm1 : Bm0;
        f16x8 Bl = kh ? Bl1 : Bl0;
        C2[mt] = __builtin_amdgcn_mfma_f32_16x16x32_f16(Ah, Bl, C2[mt], 0, 0, 0);
        C2[mt] = __builtin_amdgcn_mfma_f32_16x16x32_f16(Al, Bh, C2[mt], 0, 0, 0);
        C2[mt] = __builtin_amdgcn_mfma_f32_16x16x32_f16(Am, Bm, C2[mt], 0, 0, 0);
        C1[mt] = __builtin_amdgcn_mfma_f32_16x16x32_f16(Ah, Bm, C1[mt], 0, 0, 0);
        C1[mt] = __builtin_amdgcn_mfma_f32_16x16x32_f16(Am, Bh, C1[mt], 0, 0, 0);
        C0[mt] = __builtin_amdgcn_mfma_f32_16x16x32_f16(Ah, Bh, C0[mt], 0, 0, 0);
      }
    }
    __builtin_amdgcn_s_setprio(0);

    int ib = (nt & 1) * 16 + col;
#pragma unroll
    for (int mt = 0; mt < 4; ++mt) {
#pragma unroll
      for (int r = 0; r < 4; ++r) {
        float V = C0[mt][r] + C1[mt][r] * S11 + C2[mt][r] * S22;
        float av = fabsf(V);
        int fi = (V >= 0.f) ? ib : ib + 32;   // V==0 -> +side (lower idx)
        if ((nt & 1) == 0) {
          bv[mt][r] = av; bi[mt][r] = fi;
        } else {
          if (av > bv[mt][r] || (av == bv[mt][r] && fi < bi[mt][r])) {
            bv[mt][r] = av; bi[mt][r] = fi;
          }
        }
      }
    }

    if (nt & 1) {
      int h = w * 2 + (nt >> 1);
#pragma unroll
      for (int mt = 0; mt < 4; ++mt) {
#pragma unroll
        for (int r = 0; r < 4; ++r) {
          float v = bv[mt][r]; int i_ = bi[mt][r];
#pragma unroll
          for (int d = 1; d < 16; d <<= 1) {
            float ov = __shfl_xor(v, d);
            int   oi = __shfl_xor(i_, d);
            if (ov > v || (ov == v && oi < i_)) { v = ov; i_ = oi; }
          }
          if (col == 0) {
            int t = tt * 64 + mt * 16 + kg * 4 + r;
            buckets[(bh * 8 + h) * 4096 + t] = (uint8_t)i_;
          }
        }
      }
    }
  }
}

// ============================================================
// K1b: histogram — rebuild counts with ZERO global atomics.
// block = (bh, h); per-wave private LDS histograms; each
// (bh,h,bin) is owned by exactly one block -> plain store.
// ============================================================
__global__ __launch_bounds__(256) void k_hist(const uint8_t* __restrict__ buckets,
                                              int* __restrict__ counts) {
  __shared__ int hist[4][64];
  int tid = threadIdx.x;
  int w = tid >> 6, lane = tid & 63;
  int bh = blockIdx.x >> 3, h = blockIdx.x & 7;
  hist[w][lane] = 0;
  __syncthreads();

  const uint8_t* src = buckets + (size_t)(bh * 8 + h) * 4096;
  u32x4 v = *(const u32x4*)(src + tid * 16);
#pragma unroll
  for (int j = 0; j < 4; ++j) {
    unsigned word = v[j];
    atomicAdd(&hist[w][word & 63], 1);           // LDS atomics (block-local)
    atomicAdd(&hist[w][(word >> 8) & 63], 1);
    atomicAdd(&hist[w][(word >> 16) & 63], 1);
    atomicAdd(&hist[w][(word >> 24) & 63], 1);
  }
  __syncthreads();
  if (tid < 64)
    counts[bh * 512 + h * 64 + tid] =
        hist[0][tid] + hist[1][tid] + hist[2][tid] + hist[3][tid];
}

// ============================================================
// K2a: exclusive scan (unchanged)
// ============================================================
__global__ __launch_bounds__(512) void k_scan(int* __restrict__ counts) {
  __shared__ int s[512];
  int tid = threadIdx.x;
  int bh = blockIdx.x;
  s[tid] = counts[bh * 512 + tid];
  __syncthreads();
#pragma unroll
  for (int off = 1; off < 512; off <<= 1) {
    int v = (tid >= off) ? s[tid - off] : 0;
    __syncthreads();
    s[tid] += v;
    __syncthreads();
  }
  counts[bh * 512 + tid] = (tid == 0) ? 0 : s[tid - 1];
}

// ============================================================
// K2b: stable rank + scatter (unchanged)
// ============================================================
__global__ __launch_bounds__(64) void k_rank(const uint8_t* __restrict__ buckets,
                                             const int* __restrict__ starts,
                                             int* __restrict__ sorted) {
  __shared__ uint8_t bkt[4096];
  __shared__ uint8_t lrk[4096];
  __shared__ int hist[64 * 65];
  __shared__ int sbase[64];
  int tid = threadIdx.x;
  int bh = blockIdx.x >> 3, h = blockIdx.x & 7;

  const int* src = (const int*)(buckets + (size_t)(bh * 8 + h) * 4096);
  for (int k = tid; k < 1024; k += 64) ((int*)bkt)[k] = src[k];
  sbase[tid] = starts[bh * 512 + h * 64 + tid];
  for (int k = tid; k < 64 * 65; k += 64) hist[k] = 0;
  __syncthreads();

  {
    int c = tid;
    for (int k = 0; k < 64; ++k) {
      int t = c * 64 + k;
      int bin = bkt[t];
      int r = hist[c * 65 + bin];
      hist[c * 65 + bin] = r + 1;
      lrk[t] = (uint8_t)r;
    }
  }
  __syncthreads();
  {
    int bb = tid; int run = 0;
    for (int c2 = 0; c2 < 64; ++c2) {
      int val = hist[c2 * 65 + bb];
      hist[c2 * 65 + bb] = run;
      run += val;
    }
  }
  __syncthreads();
  {
    int c = tid;
    int* dst = sorted + (size_t)bh * 32768;
    for (int k = 0; k < 64; ++k) {
      int t = c * 64 + k;
      int bin = bkt[t];
      int pos = sbase[bin] + hist[c * 65 + bin] + (int)lrk[t];
      dst[pos] = h * 4096 + t;
    }
  }
}

// ============================================================
// K3: chunked attention, fp16 MFMA (unchanged from round 5)
// ============================================================
__global__ __launch_bounds__(256, 4) void k_attn(const _Float16* __restrict__ qk16n,
                                                 const _Float16* __restrict__ v16,
                                                 const float* __restrict__ nq,
                                                 const int* __restrict__ sorted,
                                                 _Float16* __restrict__ o_buf,
                                                 float* __restrict__ lse_buf) {
  __shared__ __attribute__((aligned(16))) _Float16 kf[128 * 64];
  __shared__ __attribute__((aligned(16))) _Float16 vt[64 * 128];
  __shared__ __attribute__((aligned(16))) float pinv_s[64];
  __shared__ __attribute__((aligned(16))) int tv[128];
  __shared__ __attribute__((aligned(16))) int items[64];

  int tid = threadIdx.x;
  int bh = blockIdx.x >> 9;
  int c  = blockIdx.x & 511;

  if (tid < 128) {
    int r = tid;
    int pos = (r < 64) ? (c * 64 + r) : (((c + 511) & 511) * 64 + (r - 64));
    int item = sorted[(size_t)bh * 32768 + pos];
    tv[r] = item & 4095;
    if (r < 64) items[r] = item;
  }
  __syncthreads();

  int w = tid >> 6;
  int l = tid & 63;
  int col = l & 15;
  int kg = l >> 4;
  int rq = w * 16 + col;
  int rqx7 = rq & 7, rqx15 = rq & 15;
  int tq = tv[rq];
  float nqv = nq[(size_t)bh * 4096 + tq];

  {
    int r = tid >> 1, half = tid & 1;
    int t = tv[r];
    const f16x8* src = (const f16x8*)(qk16n + ((size_t)(bh * 4096 + t)) * 64 + half * 32);
    f16x8 d0 = src[0], d1 = src[1], d2 = src[2], d3 = src[3];
    int rx = r & 7, s0 = half * 4;
    *(f16x8*)&kf[r * 64 + (((s0 + 0) ^ rx) << 3)] = d0;
    *(f16x8*)&kf[r * 64 + (((s0 + 1) ^ rx) << 3)] = d1;
    *(f16x8*)&kf[r * 64 + (((s0 + 2) ^ rx) << 3)] = d2;
    *(f16x8*)&kf[r * 64 + (((s0 + 3) ^ rx) << 3)] = d3;
  }

  {
    int jp = tid & 63, db = tid >> 6, f0 = db * 16;
    int t0 = tv[2 * jp], t1 = tv[2 * jp + 1];
    const u32x4* s0p = (const u32x4*)(v16 + ((size_t)(bh * 4096 + t0)) * 64 + f0);
    const u32x4* s1p = (const u32x4*)(v16 + ((size_t)(bh * 4096 + t1)) * 64 + f0);
    u32x4 lo0 = s0p[0], hi0 = s0p[1];
    u32x4 lo1 = s1p[0], hi1 = s1p[1];
    int jbase = ((jp >> 2));
    int joff = (jp & 3) << 1;
#pragma unroll
    for (int i = 0; i < 16; ++i) {
      int d = f0 + i;
      unsigned a = (i < 8) ? lo0[(i >> 1) & 3] : hi0[(i >> 1) & 3];
      unsigned bsrc = (i < 8) ? lo1[(i >> 1) & 3] : hi1[(i >> 1) & 3];
      unsigned sel = (i & 1) ? 0x07060302u : 0x05040100u;
      unsigned pack = __builtin_amdgcn_perm(bsrc, a, sel);
      *(unsigned*)&vt[d * 128 + ((jbase ^ (d & 15)) << 3) + joff] = pack;
    }
  }
  __syncthreads();

  f16x8 qf[2];
#pragma unroll
  for (int ks = 0; ks < 2; ++ks)
    qf[ks] = *(f16x8*)&kf[rq * 64 + (((ks * 4 + kg) ^ rqx7) << 3)];

  f32x4 S[8];
#pragma unroll
  for (int mt = 0; mt < 8; ++mt) S[mt] = (f32x4){0.f, 0.f, 0.f, 0.f};

  __builtin_amdgcn_s_setprio(1);
#pragma unroll
  for (int mt = 0; mt < 8; ++mt) {
    int rj = mt * 16 + col;
    int rjx = rj & 7;
#pragma unroll
    for (int ks = 0; ks < 2; ++ks) {
      f16x8 a = *(f16x8*)&kf[rj * 64 + (((ks * 4 + kg) ^ rjx) << 3)];
      S[mt] = __builtin_amdgcn_mfma_f32_16x16x32_f16(a, qf[ks], S[mt], 0, 0, 0);
    }
  }
  __builtin_amdgcn_s_setprio(0);

  float vals[32];
  float mx = -1e30f;
#pragma unroll
  for (int mt = 0; mt < 8; ++mt) {
    int j0 = mt * 16 + kg * 4;
    int4 tk4 = *(int4*)&tv[j0];
    int tki[4] = {tk4.x, tk4.y, tk4.z, tk4.w};
#pragma unroll
    for (int r = 0; r < 4; ++r) {
      float d = S[mt][r] * nqv;
      if (tki[r] == tq) d = -50000.0f * LOG2E;
      vals[mt * 4 + r] = d;
      mx = fmaxf(mx, d);
    }
  }
  mx = fmaxf(mx, __shfl_xor(mx, 16));
  mx = fmaxf(mx, __shfl_xor(mx, 32));
  float ssum = 0.f;
#pragma unroll
  for (int i = 0; i < 32; ++i) {
    float e = __builtin_amdgcn_exp2f(vals[i] - mx);
    vals[i] = e;
    ssum += e;
  }
  ssum += __shfl_xor(ssum, 16);
  ssum += __shfl_xor(ssum, 32);
  if (kg == 0) {
    int item = items[rq];
    lse_buf[(size_t)(bh * 8 + (item >> 12)) * 4096 + (item & 4095)] =
        (mx + __builtin_amdgcn_logf(ssum)) * LN2;
    pinv_s[rq] = 1.f / ssum;
  }

  __syncthreads();

  _Float16* Pb = kf;
#pragma unroll
  for (int mt = 0; mt < 8; ++mt) {
    int j0 = mt * 16 + kg * 4;
    int slot = j0 >> 3;
    int off = rq * 128 + ((slot ^ rqx15) << 3) + ((kg & 1) << 2);
    f16x4 pk;
#pragma unroll
    for (int r = 0; r < 4; ++r) pk[r] = (_Float16)vals[mt * 4 + r];
    *(f16x4*)&Pb[off] = pk;
  }
  asm volatile("s_waitcnt lgkmcnt(0)" ::: "memory");

  f32x4 O[4];
#pragma unroll
  for (int nt = 0; nt < 4; ++nt) O[nt] = (f32x4){0.f, 0.f, 0.f, 0.f};
  __builtin_amdgcn_s_setprio(1);
#pragma unroll
  for (int ks = 0; ks < 4; ++ks) {
    int slot = (ks << 2) + kg;
    f16x8 pa = *(f16x8*)&Pb[rq * 128 + ((slot ^ rqx15) << 3)];
#pragma unroll
    for (int nt = 0; nt < 4; ++nt) {
      int dD = nt * 16 + col;
      f16x8 vb = *(f16x8*)&vt[dD * 128 + ((slot ^ (dD & 15)) << 3)];
      O[nt] = __builtin_amdgcn_mfma_f32_16x16x32_f16(pa, vb, O[nt], 0, 0, 0);
    }
  }
  __builtin_amdgcn_s_setprio(0);

  {
    int i0 = w * 16 + kg * 4;
    int4 it4 = *(int4*)&items[i0];
    float4 pv4 = *(float4*)&pinv_s[i0];
    int iti[4] = {it4.x, it4.y, it4.z, it4.w};
    float pvi[4] = {pv4.x, pv4.y, pv4.z, pv4.w};
#pragma unroll
    for (int r = 0; r < 4; ++r) {
      int item = iti[r];
      _Float16* orow = o_buf + ((size_t)((bh * 8 + (item >> 12)) * 4096 + (item & 4095))) * 64;
#pragma unroll
      for (int nt = 0; nt < 4; ++nt) orow[nt * 16 + col] = (_Float16)(O[nt][r] * pvi[r]);
    }
  }
}

// ============================================================
// K4: combine 8 hash rounds (unchanged)
// ============================================================
__global__ __launch_bounds__(256) void k_combine(const _Float16* __restrict__ o_buf,
                                                 const float* __restrict__ lse_buf,
                                                 float* __restrict__ out) {
  int gid = blockIdx.x * 256 + threadIdx.x;  // < 16*4096*16
  int d4 = gid & 15;
  int t  = (gid >> 4) & 4095;
  int bh = gid >> 16;

  float lx[8];
#pragma unroll
  for (int h = 0; h < 8; ++h) lx[h] = lse_buf[(size_t)(bh * 8 + h) * 4096 + t];
  float m = lx[0];
#pragma unroll
  for (int h = 1; h < 8; ++h) m = fmaxf(m, lx[h]);
  float wv[8]; float s = 0.f;
#pragma unroll
  for (int h = 0; h < 8; ++h) { wv[h] = __expf(lx[h] - m); s += wv[h]; }
  float inv = 1.f / s;

  float ax = 0.f, ay = 0.f, az = 0.f, aw = 0.f;
#pragma unroll
  for (int h = 0; h < 8; ++h) {
    f16x4 ov = *(const f16x4*)(o_buf +
        ((size_t)((bh * 8 + h) * 4096 + t)) * 64 + d4 * 4);
    ax = fmaf(wv[h], (float)ov[0], ax);
    ay = fmaf(wv[h], (float)ov[1], ay);
    az = fmaf(wv[h], (float)ov[2], az);
    aw = fmaf(wv[h], (float)ov[3], aw);
  }
  *(float4*)(out + ((size_t)(bh * 4096 + t)) * 64 + d4 * 4) =
      make_float4(ax * inv, ay * inv, az * inv, aw * inv);
}

// ============================================================
extern "C" void kernel_launch(void* const* d_in, const int* in_sizes, int n_in,
                              void* d_out, int out_size, void* d_ws, size_t ws_size,
                              hipStream_t stream) {
  const float* qk  = (const float*)d_in[0];
  // d_in[1] ("k") is unused by the reference
  const float* vin = (const float*)d_in[2];
  const float* rot = (const float*)d_in[3];

  uint8_t* ws = (uint8_t*)d_ws;
  uint8_t*  buckets = ws + WS_BUCKETS;
  int*      counts  = (int*)(ws + WS_STARTS);
  int*      sorted  = (int*)(ws + WS_SORTED);
  float*    lse_buf = (float*)(ws + WS_LSE);
  _Float16* o_buf   = (_Float16*)(ws + WS_O);
  _Float16* qk16n   = (_Float16*)(ws + WS_QK16);
  _Float16* v16     = (_Float16*)(ws + WS_V16);
  float*    nqbuf   = (float*)(ws + WS_NQ);
  _Float16* qsh     = (_Float16*)(ws + WS_QSH);
  _Float16* qsm     = (_Float16*)(ws + WS_QSM);
  _Float16* qsl     = (_Float16*)(ws + WS_QSL);
  _Float16* rth     = (_Float16*)(ws + WS_RTH);
  _Float16* rtm     = (_Float16*)(ws + WS_RTM);
  _Float16* rtl     = (_Float16*)(ws + WS_RTL);
  float*    out     = (float*)d_out;

  k_rotsplit<<<1, 256, 0, stream>>>(rot, rth, rtm, rtl);
  k_prep<<<8192, 128, 0, stream>>>(qk, vin, qk16n, v16, nqbuf, qsh, qsm, qsl);
  k_hash2<<<BHN * 64, 256, 0, stream>>>(qsh, qsm, qsl, rth, rtm, rtl, buckets);
  k_hist<<<BHN * NHASH, 256, 0, stream>>>(buckets, counts);
  k_scan<<<BHN, 512, 0, stream>>>(counts);
  k_rank<<<BHN * NHASH, 64, 0, stream>>>(buckets, counts, sorted);
  k_attn<<<BHN * NCHUNK, 256, 0, stream>>>(qk16n, v16, nqbuf, sorted, o_buf, lse_buf);
  k_combine<<<4096, 256, 0, stream>>>(o_buf, lse_buf, out);
}

// Round 15
// 144.776 us; speedup vs baseline: 1.5111x; 1.0447x over previous
//
#include <hip/hip_runtime.h>
#include <stdint.h>

// ---------------- problem constants ----------------
#define BHN 16          // b*h flat batch
#define TLEN 4096
#define EDIM 64
#define NHASH 8
#define NBUCK 64
#define GBUCK 512
#define NCHUNK 512
#define NITEMS 32768

// ---------------- workspace layout (bytes) ----------------
#define WS_BUCKETS 0u                 // 16*8*4096 u8          = 524288
#define WS_STARTS  524288u            // 16*512 int            = 32768
#define WS_SORTED  557056u            // 16*32768 int          = 2097152
#define WS_LSE     2654208u           // 16*8*4096 f32         = 2097152
#define WS_O       4751360u           // 16*8*4096*64 fp16     = 67108864
#define WS_QK16    71860224u          // 16*4096*64 fp16       = 8388608
#define WS_V16     80248832u          // 16*4096*64 fp16       = 8388608
#define WS_NQ      88637440u          // 16*4096 f32           = 262144
#define WS_QSH     88899584u          // 16*4096*64 fp16       = 8388608
#define WS_QSM     97288192u          // 16*4096*64 fp16       = 8388608
#define WS_QSL     105676800u         // 16*4096*64 fp16       = 8388608
#define WS_RTH     114065408u         // 256*64 fp16           = 32768
#define WS_RTM     114098176u         // 256*64 fp16           = 32768
#define WS_RTL     114130944u         // 256*64 fp16           = 32768
// end ~114.2 MB

typedef __attribute__((ext_vector_type(4))) float f32x4;
typedef __attribute__((ext_vector_type(8))) _Float16 f16x8;     // MFMA A/B frag
typedef __attribute__((ext_vector_type(4))) _Float16 f16x4;
typedef __attribute__((ext_vector_type(4))) unsigned u32x4;

#define LOG2E 1.44269504088896f
#define LN2   0.69314718055995f
#define S11   4.8828125e-4f            // 2^-11
#define S22   2.384185791015625e-7f    // 2^-22

// exact fp16 triple split: x = h + m*2^-11 + l*2^-22 (+ ~2^-33 residual).
static __device__ __forceinline__ void split3(float x, _Float16& h0, _Float16& m0, _Float16& l0) {
  h0 = (_Float16)x;
  float r1 = x - (float)h0;                 // exact (Sterbenz)
  m0 = (_Float16)(r1 * 2048.0f);            // scaled 2^11, exact pow2 scale
  float r2 = r1 - (float)m0 * (1.0f / 2048.0f);  // exact
  l0 = (_Float16)(r2 * 4194304.0f);         // scaled 2^22
}

// ============================================================
// K0: prep — normalize qk rows to fp16 + |q|*log2e + v fp16,
// plus exact fp16 triple-split of raw qk for the MFMA hash.
// ============================================================
__global__ __launch_bounds__(128) void k_prep(const float* __restrict__ qk,
                                              const float* __restrict__ vin,
                                              _Float16* __restrict__ qk16n,
                                              _Float16* __restrict__ v16,
                                              float* __restrict__ nq,
                                              _Float16* __restrict__ qsh,
                                              _Float16* __restrict__ qsm,
                                              _Float16* __restrict__ qsl) {
  int blk = blockIdx.x;             // 8192 = b*4096 + t
  int b = blk >> 12, t = blk & 4095;
  int tid = threadIdx.x;
  int h = tid >> 4, e4 = tid & 15;

  size_t in_base = ((size_t)((b * 4096 + t) * 8 + h)) * 64 + e4 * 4;
  float4 qv = *(const float4*)(qk + in_base);
  float ss = qv.x * qv.x + qv.y * qv.y + qv.z * qv.z + qv.w * qv.w;
  ss += __shfl_xor(ss, 1);
  ss += __shfl_xor(ss, 2);
  ss += __shfl_xor(ss, 4);
  ss += __shfl_xor(ss, 8);
  float nrm = fmaxf(sqrtf(ss), 1e-12f);
  float inv = 1.f / nrm;

  size_t out_base = ((size_t)((b * 8 + h) * 4096 + t)) * 64 + e4 * 4;
  f16x4 qh;
  qh[0] = (_Float16)(qv.x * inv); qh[1] = (_Float16)(qv.y * inv);
  qh[2] = (_Float16)(qv.z * inv); qh[3] = (_Float16)(qv.w * inv);
  *(f16x4*)(qk16n + out_base) = qh;
  if (e4 == 0) nq[(size_t)(b * 8 + h) * 4096 + t] = nrm * LOG2E;

  {
    float xs[4] = {qv.x, qv.y, qv.z, qv.w};
    f16x4 sh_, sm_, sl_;
#pragma unroll
    for (int i = 0; i < 4; ++i) {
      _Float16 h0, m0, l0;
      split3(xs[i], h0, m0, l0);
      sh_[i] = h0; sm_[i] = m0; sl_[i] = l0;
    }
    *(f16x4*)(qsh + out_base) = sh_;
    *(f16x4*)(qsm + out_base) = sm_;
    *(f16x4*)(qsl + out_base) = sl_;
  }

  float4 vv = *(const float4*)(vin + in_base);
  f16x4 vh;
  vh[0] = (_Float16)vv.x; vh[1] = (_Float16)vv.y;
  vh[2] = (_Float16)vv.z; vh[3] = (_Float16)vv.w;
  *(f16x4*)(v16 + out_base) = vh;
}

// ============================================================
// K0b: transpose + triple-split rotations: rt*[n=256][f=64].
// ============================================================
__global__ __launch_bounds__(256) void k_rotsplit(const float* __restrict__ rot,
                                                  _Float16* __restrict__ rth,
                                                  _Float16* __restrict__ rtm,
                                                  _Float16* __restrict__ rtl) {
  int n = threadIdx.x;
  for (int f = 0; f < 64; ++f) {
    float x = rot[f * 256 + n];
    _Float16 h0, m0, l0;
    split3(x, h0, m0, l0);
    rth[n * 64 + f] = h0;
    rtm[n * 64 + f] = m0;
    rtl[n * 64 + f] = l0;
  }
}

// ============================================================
// K1: LSH hash via MFMA — no global atomics (r12-verified).
// ============================================================
__global__ __launch_bounds__(256) void k_hash2(const _Float16* __restrict__ qsh,
                                               const _Float16* __restrict__ qsm,
                                               const _Float16* __restrict__ qsl,
                                               const _Float16* __restrict__ rth,
                                               const _Float16* __restrict__ rtm,
                                               const _Float16* __restrict__ rtl,
                                               uint8_t* __restrict__ buckets) {
  __shared__ __attribute__((aligned(16))) _Float16 ah[64 * 64];
  __shared__ __attribute__((aligned(16))) _Float16 am[64 * 64];
  __shared__ __attribute__((aligned(16))) _Float16 al[64 * 64];

  int tid = threadIdx.x;
  int bh = blockIdx.x >> 6;
  int tt = blockIdx.x & 63;

  // ---- stage A (64 tokens x 64 f, 3 levels) ----
  {
    int r = tid & 63, fq = tid >> 6;          // fq: 16 f's each
    size_t g = ((size_t)(bh * 4096 + tt * 64 + r)) * 64 + fq * 16;
    int s0 = fq * 2, rx = r & 7;
    f16x8 x0 = *(const f16x8*)(qsh + g), x1 = *(const f16x8*)(qsh + g + 8);
    *(f16x8*)&ah[r * 64 + ((s0 ^ rx) << 3)] = x0;
    *(f16x8*)&ah[r * 64 + (((s0 + 1) ^ rx) << 3)] = x1;
    f16x8 y0 = *(const f16x8*)(qsm + g), y1 = *(const f16x8*)(qsm + g + 8);
    *(f16x8*)&am[r * 64 + ((s0 ^ rx) << 3)] = y0;
    *(f16x8*)&am[r * 64 + (((s0 + 1) ^ rx) << 3)] = y1;
    f16x8 z0 = *(const f16x8*)(qsl + g), z1 = *(const f16x8*)(qsl + g + 8);
    *(f16x8*)&al[r * 64 + ((s0 ^ rx) << 3)] = z0;
    *(f16x8*)&al[r * 64 + (((s0 + 1) ^ rx) << 3)] = z1;
  }
  __syncthreads();

  int w = tid >> 6, l = tid & 63;
  int col = l & 15, kg = l >> 4;

  float bv[4][4];
  int   bi[4][4];

#pragma unroll
  for (int nt = 0; nt < 4; ++nt) {
    int nrow = w * 64 + nt * 16 + col;
    const _Float16* bh_p = rth + nrow * 64 + kg * 8;
    const _Float16* bm_p = rtm + nrow * 64 + kg * 8;
    const _Float16* bl_p = rtl + nrow * 64 + kg * 8;
    f16x8 Bh0 = *(const f16x8*)(bh_p),      Bh1 = *(const f16x8*)(bh_p + 32);
    f16x8 Bm0 = *(const f16x8*)(bm_p),      Bm1 = *(const f16x8*)(bm_p + 32);
    f16x8 Bl0 = *(const f16x8*)(bl_p),      Bl1 = *(const f16x8*)(bl_p + 32);

    f32x4 C0[4], C1[4], C2[4];
#pragma unroll
    for (int mt = 0; mt < 4; ++mt) {
      C0[mt] = (f32x4){0.f, 0.f, 0.f, 0.f};
      C1[mt] = (f32x4){0.f, 0.f, 0.f, 0.f};
      C2[mt] = (f32x4){0.f, 0.f, 0.f, 0.f};
    }

    __builtin_amdgcn_s_setprio(1);
#pragma unroll
    for (int mt = 0; mt < 4; ++mt) {
      int ar = mt * 16 + col, arx = ar & 7;
#pragma unroll
      for (int kh = 0; kh < 2; ++kh) {
        int slot = kh * 4 + kg;
        f16x8 Ah = *(f16x8*)&ah[ar * 64 + ((slot ^ arx) << 3)];
        f16x8 Am = *(f16x8*)&am[ar * 64 + ((slot ^ arx) << 3)];
        f16x8 Al = *(f16x8*)&al[ar * 64 + ((slot ^ arx) << 3)];
        f16x8 Bh = kh ? Bh1 : Bh0;
        f16x8 Bm = kh ? Bm1 : Bm0;
        f16x8 Bl = kh ? Bl1 : Bl0;
        C2[mt] = __builtin_amdgcn_mfma_f32_16x16x32_f16(Ah, Bl, C2[mt], 0, 0, 0);
        C2[mt] = __builtin_amdgcn_mfma_f32_16x16x32_f16(Al, Bh, C2[mt], 0, 0, 0);
        C2[mt] = __builtin_amdgcn_mfma_f32_16x16x32_f16(Am, Bm, C2[mt], 0, 0, 0);
        C1[mt] = __builtin_amdgcn_mfma_f32_16x16x32_f16(Ah, Bm, C1[mt], 0, 0, 0);
        C1[mt] = __builtin_amdgcn_mfma_f32_16x16x32_f16(Am, Bh, C1[mt], 0, 0, 0);
        C0[mt] = __builtin_amdgcn_mfma_f32_16x16x32_f16(Ah, Bh, C0[mt], 0, 0, 0);
      }
    }
    __builtin_amdgcn_s_setprio(0);

    int ib = (nt & 1) * 16 + col;
#pragma unroll
    for (int mt = 0; mt < 4; ++mt) {
#pragma unroll
      for (int r = 0; r < 4; ++r) {
        float V = C0[mt][r] + C1[mt][r] * S11 + C2[mt][r] * S22;
        float av = fabsf(V);
        int fi = (V >= 0.f) ? ib : ib + 32;   // V==0 -> +side (lower idx)
        if ((nt & 1) == 0) {
          bv[mt][r] = av; bi[mt][r] = fi;
        } else {
          if (av > bv[mt][r] || (av == bv[mt][r] && fi < bi[mt][r])) {
            bv[mt][r] = av; bi[mt][r] = fi;
          }
        }
      }
    }

    if (nt & 1) {
      int h = w * 2 + (nt >> 1);
#pragma unroll
      for (int mt = 0; mt < 4; ++mt) {
#pragma unroll
        for (int r = 0; r < 4; ++r) {
          float v = bv[mt][r]; int i_ = bi[mt][r];
#pragma unroll
          for (int d = 1; d < 16; d <<= 1) {
            float ov = __shfl_xor(v, d);
            int   oi = __shfl_xor(i_, d);
            if (ov > v || (ov == v && oi < i_)) { v = ov; i_ = oi; }
          }
          if (col == 0) {
            int t = tt * 64 + mt * 16 + kg * 4 + r;
            buckets[(bh * 8 + h) * 4096 + t] = (uint8_t)i_;
          }
        }
      }
    }
  }
}

// ============================================================
// K1b: histogram — zero global atomics (r12-verified).
// ============================================================
__global__ __launch_bounds__(256) void k_hist(const uint8_t* __restrict__ buckets,
                                              int* __restrict__ counts) {
  __shared__ int hist[4][64];
  int tid = threadIdx.x;
  int w = tid >> 6, lane = tid & 63;
  int bh = blockIdx.x >> 3, h = blockIdx.x & 7;
  hist[w][lane] = 0;
  __syncthreads();

  const uint8_t* src = buckets + (size_t)(bh * 8 + h) * 4096;
  u32x4 v = *(const u32x4*)(src + tid * 16);
#pragma unroll
  for (int j = 0; j < 4; ++j) {
    unsigned word = v[j];
    atomicAdd(&hist[w][word & 63], 1);           // LDS atomics (block-local)
    atomicAdd(&hist[w][(word >> 8) & 63], 1);
    atomicAdd(&hist[w][(word >> 16) & 63], 1);
    atomicAdd(&hist[w][(word >> 24) & 63], 1);
  }
  __syncthreads();
  if (tid < 64)
    counts[bh * 512 + h * 64 + tid] =
        hist[0][tid] + hist[1][tid] + hist[2][tid] + hist[3][tid];
}

// ============================================================
// K2a: exclusive scan (unchanged)
// ============================================================
__global__ __launch_bounds__(512) void k_scan(int* __restrict__ counts) {
  __shared__ int s[512];
  int tid = threadIdx.x;
  int bh = blockIdx.x;
  s[tid] = counts[bh * 512 + tid];
  __syncthreads();
#pragma unroll
  for (int off = 1; off < 512; off <<= 1) {
    int v = (tid >= off) ? s[tid - off] : 0;
    __syncthreads();
    s[tid] += v;
    __syncthreads();
  }
  counts[bh * 512 + tid] = (tid == 0) ? 0 : s[tid - 1];
}

// ============================================================
// K2b: stable rank + scatter (unchanged)
// ============================================================
__global__ __launch_bounds__(64) void k_rank(const uint8_t* __restrict__ buckets,
                                             const int* __restrict__ starts,
                                             int* __restrict__ sorted) {
  __shared__ uint8_t bkt[4096];
  __shared__ uint8_t lrk[4096];
  __shared__ int hist[64 * 65];
  __shared__ int sbase[64];
  int tid = threadIdx.x;
  int bh = blockIdx.x >> 3, h = blockIdx.x & 7;

  const int* src = (const int*)(buckets + (size_t)(bh * 8 + h) * 4096);
  for (int k = tid; k < 1024; k += 64) ((int*)bkt)[k] = src[k];
  sbase[tid] = starts[bh * 512 + h * 64 + tid];
  for (int k = tid; k < 64 * 65; k += 64) hist[k] = 0;
  __syncthreads();

  {
    int c = tid;
    for (int k = 0; k < 64; ++k) {
      int t = c * 64 + k;
      int bin = bkt[t];
      int r = hist[c * 65 + bin];
      hist[c * 65 + bin] = r + 1;
      lrk[t] = (uint8_t)r;
    }
  }
  __syncthreads();
  {
    int bb = tid; int run = 0;
    for (int c2 = 0; c2 < 64; ++c2) {
      int val = hist[c2 * 65 + bb];
      hist[c2 * 65 + bb] = run;
      run += val;
    }
  }
  __syncthreads();
  {
    int c = tid;
    int* dst = sorted + (size_t)bh * 32768;
    for (int k = 0; k < 64; ++k) {
      int t = c * 64 + k;
      int bin = bkt[t];
      int pos = sbase[bin] + hist[c * 65 + bin] + (int)lrk[t];
      dst[pos] = h * 4096 + t;
    }
  }
}

// ============================================================
// K3: chunked attention, fp16 MFMA.
// XCD-locality remap (T1): blockIdx = c*16 + bh, so XCD =
// blk%8 = bh%8 -> all 512 chunks of a bh share one XCD's L2
// (2 bh x 1MB gather set per 4MB L2). The 16x gather reuse
// per bh was previously spread over all 8 XCDs (r12: FETCH
// 62MB vs 17MB unique).
// ============================================================
__global__ __launch_bounds__(256, 4) void k_attn(const _Float16* __restrict__ qk16n,
                                                 const _Float16* __restrict__ v16,
                                                 const float* __restrict__ nq,
                                                 const int* __restrict__ sorted,
                                                 _Float16* __restrict__ o_buf,
                                                 float* __restrict__ lse_buf) {
  __shared__ __attribute__((aligned(16))) _Float16 kf[128 * 64];
  __shared__ __attribute__((aligned(16))) _Float16 vt[64 * 128];
  __shared__ __attribute__((aligned(16))) float pinv_s[64];
  __shared__ __attribute__((aligned(16))) int tv[128];
  __shared__ __attribute__((aligned(16))) int items[64];

  int tid = threadIdx.x;
  int bh = blockIdx.x & 15;      // XCD-local decode
  int c  = blockIdx.x >> 4;

  if (tid < 128) {
    int r = tid;
    int pos = (r < 64) ? (c * 64 + r) : (((c + 511) & 511) * 64 + (r - 64));
    int item = sorted[(size_t)bh * 32768 + pos];
    tv[r] = item & 4095;
    if (r < 64) items[r] = item;
  }
  __syncthreads();

  int w = tid >> 6;
  int l = tid & 63;
  int col = l & 15;
  int kg = l >> 4;
  int rq = w * 16 + col;
  int rqx7 = rq & 7, rqx15 = rq & 15;
  int tq = tv[rq];
  float nqv = nq[(size_t)bh * 4096 + tq];

  {
    int r = tid >> 1, half = tid & 1;
    int t = tv[r];
    const f16x8* src = (const f16x8*)(qk16n + ((size_t)(bh * 4096 + t)) * 64 + half * 32);
    f16x8 d0 = src[0], d1 = src[1], d2 = src[2], d3 = src[3];
    int rx = r & 7, s0 = half * 4;
    *(f16x8*)&kf[r * 64 + (((s0 + 0) ^ rx) << 3)] = d0;
    *(f16x8*)&kf[r * 64 + (((s0 + 1) ^ rx) << 3)] = d1;
    *(f16x8*)&kf[r * 64 + (((s0 + 2) ^ rx) << 3)] = d2;
    *(f16x8*)&kf[r * 64 + (((s0 + 3) ^ rx) << 3)] = d3;
  }

  {
    int jp = tid & 63, db = tid >> 6, f0 = db * 16;
    int t0 = tv[2 * jp], t1 = tv[2 * jp + 1];
    const u32x4* s0p = (const u32x4*)(v16 + ((size_t)(bh * 4096 + t0)) * 64 + f0);
    const u32x4* s1p = (const u32x4*)(v16 + ((size_t)(bh * 4096 + t1)) * 64 + f0);
    u32x4 lo0 = s0p[0], hi0 = s0p[1];
    u32x4 lo1 = s1p[0], hi1 = s1p[1];
    int jbase = ((jp >> 2));
    int joff = (jp & 3) << 1;
#pragma unroll
    for (int i = 0; i < 16; ++i) {
      int d = f0 + i;
      unsigned a = (i < 8) ? lo0[(i >> 1) & 3] : hi0[(i >> 1) & 3];
      unsigned bsrc = (i < 8) ? lo1[(i >> 1) & 3] : hi1[(i >> 1) & 3];
      unsigned sel = (i & 1) ? 0x07060302u : 0x05040100u;
      unsigned pack = __builtin_amdgcn_perm(bsrc, a, sel);
      *(unsigned*)&vt[d * 128 + ((jbase ^ (d & 15)) << 3) + joff] = pack;
    }
  }
  __syncthreads();

  f16x8 qf[2];
#pragma unroll
  for (int ks = 0; ks < 2; ++ks)
    qf[ks] = *(f16x8*)&kf[rq * 64 + (((ks * 4 + kg) ^ rqx7) << 3)];

  f32x4 S[8];
#pragma unroll
  for (int mt = 0; mt < 8; ++mt) S[mt] = (f32x4){0.f, 0.f, 0.f, 0.f};

  __builtin_amdgcn_s_setprio(1);
#pragma unroll
  for (int mt = 0; mt < 8; ++mt) {
    int rj = mt * 16 + col;
    int rjx = rj & 7;
#pragma unroll
    for (int ks = 0; ks < 2; ++ks) {
      f16x8 a = *(f16x8*)&kf[rj * 64 + (((ks * 4 + kg) ^ rjx) << 3)];
      S[mt] = __builtin_amdgcn_mfma_f32_16x16x32_f16(a, qf[ks], S[mt], 0, 0, 0);
    }
  }
  __builtin_amdgcn_s_setprio(0);

  float vals[32];
  float mx = -1e30f;
#pragma unroll
  for (int mt = 0; mt < 8; ++mt) {
    int j0 = mt * 16 + kg * 4;
    int4 tk4 = *(int4*)&tv[j0];
    int tki[4] = {tk4.x, tk4.y, tk4.z, tk4.w};
#pragma unroll
    for (int r = 0; r < 4; ++r) {
      float d = S[mt][r] * nqv;
      if (tki[r] == tq) d = -50000.0f * LOG2E;
      vals[mt * 4 + r] = d;
      mx = fmaxf(mx, d);
    }
  }
  mx = fmaxf(mx, __shfl_xor(mx, 16));
  mx = fmaxf(mx, __shfl_xor(mx, 32));
  float ssum = 0.f;
#pragma unroll
  for (int i = 0; i < 32; ++i) {
    float e = __builtin_amdgcn_exp2f(vals[i] - mx);
    vals[i] = e;
    ssum += e;
  }
  ssum += __shfl_xor(ssum, 16);
  ssum += __shfl_xor(ssum, 32);
  if (kg == 0) {
    int item = items[rq];
    lse_buf[(size_t)(bh * 8 + (item >> 12)) * 4096 + (item & 4095)] =
        (mx + __builtin_amdgcn_logf(ssum)) * LN2;
    pinv_s[rq] = 1.f / ssum;
  }

  __syncthreads();

  _Float16* Pb = kf;
#pragma unroll
  for (int mt = 0; mt < 8; ++mt) {
    int j0 = mt * 16 + kg * 4;
    int slot = j0 >> 3;
    int off = rq * 128 + ((slot ^ rqx15) << 3) + ((kg & 1) << 2);
    f16x4 pk;
#pragma unroll
    for (int r = 0; r < 4; ++r) pk[r] = (_Float16)vals[mt * 4 + r];
    *(f16x4*)&Pb[off] = pk;
  }
  asm volatile("s_waitcnt lgkmcnt(0)" ::: "memory");

  f32x4 O[4];
#pragma unroll
  for (int nt = 0; nt < 4; ++nt) O[nt] = (f32x4){0.f, 0.f, 0.f, 0.f};
  __builtin_amdgcn_s_setprio(1);
#pragma unroll
  for (int ks = 0; ks < 4; ++ks) {
    int slot = (ks << 2) + kg;
    f16x8 pa = *(f16x8*)&Pb[rq * 128 + ((slot ^ rqx15) << 3)];
#pragma unroll
    for (int nt = 0; nt < 4; ++nt) {
      int dD = nt * 16 + col;
      f16x8 vb = *(f16x8*)&vt[dD * 128 + ((slot ^ (dD & 15)) << 3)];
      O[nt] = __builtin_amdgcn_mfma_f32_16x16x32_f16(pa, vb, O[nt], 0, 0, 0);
    }
  }
  __builtin_amdgcn_s_setprio(0);

  {
    int i0 = w * 16 + kg * 4;
    int4 it4 = *(int4*)&items[i0];
    float4 pv4 = *(float4*)&pinv_s[i0];
    int iti[4] = {it4.x, it4.y, it4.z, it4.w};
    float pvi[4] = {pv4.x, pv4.y, pv4.z, pv4.w};
#pragma unroll
    for (int r = 0; r < 4; ++r) {
      int item = iti[r];
      _Float16* orow = o_buf + ((size_t)((bh * 8 + (item >> 12)) * 4096 + (item & 4095))) * 64;
#pragma unroll
      for (int nt = 0; nt < 4; ++nt) orow[nt * 16 + col] = (_Float16)(O[nt][r] * pvi[r]);
    }
  }
}

// ============================================================
// K4: combine 8 hash rounds (unchanged — streaming, no reuse,
// so no XCD remap benefit)
// ============================================================
__global__ __launch_bounds__(256) void k_combine(const _Float16* __restrict__ o_buf,
                                                 const float* __restrict__ lse_buf,
                                                 float* __restrict__ out) {
  int gid = blockIdx.x * 256 + threadIdx.x;  // < 16*4096*16
  int d4 = gid & 15;
  int t  = (gid >> 4) & 4095;
  int bh = gid >> 16;

  float lx[8];
#pragma unroll
  for (int h = 0; h < 8; ++h) lx[h] = lse_buf[(size_t)(bh * 8 + h) * 4096 + t];
  float m = lx[0];
#pragma unroll
  for (int h = 1; h < 8; ++h) m = fmaxf(m, lx[h]);
  float wv[8]; float s = 0.f;
#pragma unroll
  for (int h = 0; h < 8; ++h) { wv[h] = __expf(lx[h] - m); s += wv[h]; }
  float inv = 1.f / s;

  float ax = 0.f, ay = 0.f, az = 0.f, aw = 0.f;
#pragma unroll
  for (int h = 0; h < 8; ++h) {
    f16x4 ov = *(const f16x4*)(o_buf +
        ((size_t)((bh * 8 + h) * 4096 + t)) * 64 + d4 * 4);
    ax = fmaf(wv[h], (float)ov[0], ax);
    ay = fmaf(wv[h], (float)ov[1], ay);
    az = fmaf(wv[h], (float)ov[2], az);
    aw = fmaf(wv[h], (float)ov[3], aw);
  }
  *(float4*)(out + ((size_t)(bh * 4096 + t)) * 64 + d4 * 4) =
      make_float4(ax * inv, ay * inv, az * inv, aw * inv);
}

// ============================================================
extern "C" void kernel_launch(void* const* d_in, const int* in_sizes, int n_in,
                              void* d_out, int out_size, void* d_ws, size_t ws_size,
                              hipStream_t stream) {
  const float* qk  = (const float*)d_in[0];
  // d_in[1] ("k") is unused by the reference
  const float* vin = (const float*)d_in[2];
  const float* rot = (const float*)d_in[3];

  uint8_t* ws = (uint8_t*)d_ws;
  uint8_t*  buckets = ws + WS_BUCKETS;
  int*      counts  = (int*)(ws + WS_STARTS);
  int*      sorted  = (int*)(ws + WS_SORTED);
  float*    lse_buf = (float*)(ws + WS_LSE);
  _Float16* o_buf   = (_Float16*)(ws + WS_O);
  _Float16* qk16n   = (_Float16*)(ws + WS_QK16);
  _Float16* v16     = (_Float16*)(ws + WS_V16);
  float*    nqbuf   = (float*)(ws + WS_NQ);
  _Float16* qsh     = (_Float16*)(ws + WS_QSH);
  _Float16* qsm     = (_Float16*)(ws + WS_QSM);
  _Float16* qsl     = (_Float16*)(ws + WS_QSL);
  _Float16* rth     = (_Float16*)(ws + WS_RTH);
  _Float16* rtm     = (_Float16*)(ws + WS_RTM);
  _Float16* rtl     = (_Float16*)(ws + WS_RTL);
  float*    out     = (float*)d_out;

  k_rotsplit<<<1, 256, 0, stream>>>(rot, rth, rtm, rtl);
  k_prep<<<8192, 128, 0, stream>>>(qk, vin, qk16n, v16, nqbuf, qsh, qsm, qsl);
  k_hash2<<<BHN * 64, 256, 0, stream>>>(qsh, qsm, qsl, rth, rtm, rtl, buckets);
  k_hist<<<BHN * NHASH, 256, 0, stream>>>(buckets, counts);
  k_scan<<<BHN, 512, 0, stream>>>(counts);
  k_rank<<<BHN * NHASH, 64, 0, stream>>>(buckets, counts, sorted);
  k_attn<<<BHN * NCHUNK, 256, 0, stream>>>(qk16n, v16, nqbuf, sorted, o_buf, lse_buf);
  k_combine<<<4096, 256, 0, stream>>>(o_buf, lse_buf, out);
}